// Round 17
// baseline (329.416 us; speedup 1.0000x reference)
//
#include <hip/hip_runtime.h>
#include <math.h>

// Problem constants (match reference)
#define BATCH 4
#define NK    100000
#define IH    640
#define IW    472
#define GH    1280          // oversampled grid rows = 2*IH   (1280 = 20*8*8)
#define GW    944           // oversampled grid cols = 2*IW   (944  = 59*16)
#define GWP   952           // padded row stride: 8 echo cols (window reach <= 951)
#define JW    6             // KB kernel width

// ws layout (bytes):
//   [0..]      tw (2224 v2f), kb table, apod tables   (TW_RESERVE = 64 KB)
//   [64K..]    packed-bf16 grid, 4 batches (19.5 MB)
//   [32M..]    sort scratch: hist, curs, bkt, perm
#define TW1280_OFF 0
#define TW944_OFF  1280
#define KB_OFF_B   18432
#define AX_OFF_B   34944
#define AY_OFF_B   37504
#define TW_RESERVE_BYTES 65536

#define NBKT   (BATCH * 160)           // 640 buckets: b*160 + (m0>>6)*8 + (aw>>7)
#define HIST_OFF_B  (32u * 1024 * 1024)
#define CURS_OFF_B  (HIST_OFF_B + 4096)
#define BKT_OFF_B   (HIST_OFF_B + 8192)
#define PERM_OFF_B  (BKT_OFF_B + 1601536)
#define SORT_END_B  (PERM_OFF_B + 1601536)

#define KBN 4095             // table scale: idx = z*KBN, entries 0..4096
#define NC 4                 // columns per fft_col block

typedef float v2f __attribute__((ext_vector_type(2)));
typedef float v4f __attribute__((ext_vector_type(4)));

static __device__ __forceinline__ float beta_f() {
    return (float)(M_PI * 4.410215414239989);   // pi*sqrt(19.45)
}

// Abramowitz & Stegun I0 approximation (rel err < 2e-7), x >= 0
static __device__ __forceinline__ float i0f_dev(float x) {
    if (x < 3.75f) {
        float t = x * (1.0f / 3.75f);
        t *= t;
        return 1.0f + t*(3.5156229f + t*(3.0899424f + t*(1.2067492f +
               t*(0.2659732f + t*(0.0360768f + t*0.0045813f)))));
    } else {
        float t = 3.75f / x;
        float p = 0.39894228f + t*(0.01328592f + t*(0.00225319f + t*(-0.00157565f +
                  t*(0.00916281f + t*(-0.02057706f + t*(0.02635537f +
                  t*(-0.01647633f + t*0.00392377f)))))));
        return p * expf(x) / sqrtf(x);
    }
}

// ---- packed complex helpers
static __device__ __forceinline__ v2f perp(v2f w) { return (v2f){-w.y, w.x}; }
static __device__ __forceinline__ v2f cmulp(v2f x, v2f w, v2f wp) {
    v2f xr = __builtin_shufflevector(x, x, 0, 0);
    v2f xi = __builtin_shufflevector(x, x, 1, 1);
    return xr * w + xi * wp;
}
static __device__ __forceinline__ v2f cmul(v2f a, v2f b) { return cmulp(a, b, perp(b)); }
static __device__ __forceinline__ void cmacp(v2f& acc, v2f x, v2f w, v2f wp) {
    v2f xr = __builtin_shufflevector(x, x, 0, 0);
    v2f xi = __builtin_shufflevector(x, x, 1, 1);
    acc += xr * w;
    acc += xi * wp;
}

// float <-> bf16 pack
static __device__ __forceinline__ unsigned int f2bf(float f) {
    unsigned int u = __float_as_uint(f);
    return (u + 0x7FFFu + ((u >> 16) & 1u)) >> 16;
}
static __device__ __forceinline__ unsigned int packbf(v2f v) {
    return f2bf(v.x) | (f2bf(v.y) << 16);
}
static __device__ __forceinline__ v2f unpackbf(unsigned int p) {
    return (v2f){__uint_as_float(p << 16), __uint_as_float(p & 0xFFFF0000u)};
}

// DFT4 (W4 = -i)
static __device__ __forceinline__ void dft4(v2f a0, v2f a1, v2f a2, v2f a3,
                                            v2f& o0, v2f& o1, v2f& o2, v2f& o3)
{
    v2f t0 = a0 + a2, t1 = a0 - a2;
    v2f t2 = a1 + a3, t3 = a1 - a3;
    o0 = t0 + t2;
    o2 = t0 - t2;
    v2f nit3 = (v2f){t3.y, -t3.x};
    o1 = t1 + nit3;
    o3 = t1 - nit3;
}

static __device__ __forceinline__ void dft8(const v2f* b, v2f* X)
{
    v2f e0, e1, e2, e3, o0, o1, o2, o3;
    dft4(b[0], b[2], b[4], b[6], e0, e1, e2, e3);
    dft4(b[1], b[3], b[5], b[7], o0, o1, o2, o3);
    const float C = 0.70710678118654752f;
    v2f m1 = cmulp(o1, (v2f){ C, -C}, (v2f){C,  C});
    v2f m2 = (v2f){o2.y, -o2.x};
    v2f m3 = cmulp(o3, (v2f){-C, -C}, (v2f){C, -C});
    X[0] = e0 + o0; X[4] = e0 - o0;
    X[1] = e1 + m1; X[5] = e1 - m1;
    X[2] = e2 + m2; X[6] = e2 - m2;
    X[3] = e3 + m3; X[7] = e3 - m3;
}

// DFT5 (Winograd-style even/odd split)
static __device__ __forceinline__ void dft5(v2f a0, v2f a1, v2f a2, v2f a3, v2f a4,
                                            v2f* X)
{
    const float c1 = 0.30901699437494742f, s1 = 0.95105651629515353f;
    const float c2 = -0.80901699437494742f, s2 = 0.58778525229247312f;
    v2f t1 = a1 + a4, d1 = a1 - a4;
    v2f t2 = a2 + a3, d2 = a2 - a3;
    X[0] = a0 + t1 + t2;
    v2f e1 = a0 + c1 * t1 + c2 * t2;
    v2f o1 = s1 * d1 + s2 * d2;
    v2f e2 = a0 + c2 * t1 + c1 * t2;
    v2f o2 = s2 * d1 - s1 * d2;
    X[1] = (v2f){e1.x + o1.y, e1.y - o1.x};
    X[4] = (v2f){e1.x - o1.y, e1.y + o1.x};
    X[2] = (v2f){e2.x + o2.y, e2.y - o2.x};
    X[3] = (v2f){e2.x - o2.y, e2.y + o2.x};
}

static __device__ __forceinline__ void dft16(const v2f* a, v2f* X)
{
    v2f y[4][4];
    #pragma unroll
    for (int n2 = 0; n2 < 4; ++n2)
        dft4(a[n2], a[4 + n2], a[8 + n2], a[12 + n2],
             y[n2][0], y[n2][1], y[n2][2], y[n2][3]);
    const float C  = 0.70710678118654752f;
    const float c1 = 0.92387953251128676f, s1 = 0.38268343236508977f;
    y[1][1] = cmulp(y[1][1], (v2f){ c1, -s1}, (v2f){ s1,  c1});
    y[1][2] = cmulp(y[1][2], (v2f){  C,  -C}, (v2f){  C,   C});
    y[1][3] = cmulp(y[1][3], (v2f){ s1, -c1}, (v2f){ c1,  s1});
    y[2][1] = cmulp(y[2][1], (v2f){  C,  -C}, (v2f){  C,   C});
    y[2][2] = (v2f){y[2][2].y, -y[2][2].x};
    y[2][3] = cmulp(y[2][3], (v2f){ -C,  -C}, (v2f){  C,  -C});
    y[3][1] = cmulp(y[3][1], (v2f){ s1, -c1}, (v2f){ c1,  s1});
    y[3][2] = cmulp(y[3][2], (v2f){ -C,  -C}, (v2f){  C,  -C});
    y[3][3] = cmulp(y[3][3], (v2f){-c1,  s1}, (v2f){-s1, -c1});
    #pragma unroll
    for (int k1 = 0; k1 < 4; ++k1)
        dft4(y[0][k1], y[1][k1], y[2][k1], y[3][k1],
             X[k1], X[k1 + 4], X[k1 + 8], X[k1 + 12]);
}

// table lerp weight
static __device__ __forceinline__ float kbw(const float* kt, float zz) {
    float t = fmaxf(zz * (float)KBN, 0.0f);
    int i = (int)t;
    float fr = t - (float)i;
    float w = fmaf(fr, kt[i + 1] - kt[i], kt[i]);
    return (zz > 0.f) ? w : 0.f;
}

// ---------------------------------------------------------------------------
// Kernel 0: setup — twiddles, KB table, apod tables, zero sort histogram
// ---------------------------------------------------------------------------
__global__ __launch_bounds__(256) void setup_kernel(
        float2* __restrict__ tw, float* __restrict__ kbt,
        float* __restrict__ axt, float* __restrict__ ayt,
        int* __restrict__ hist)
{
    int idx = blockIdx.x * 256 + threadIdx.x;
    const double TWO_PI = 6.283185307179586476925286766559;
    const float BETA = beta_f();
    const float B2 = (float)(M_PI * M_PI * 19.45);
    const float SCALE = (float)(1.0 / 1099.236098591787);

    if (idx < 1280) {
        double a = -TWO_PI * ((double)idx / 1280.0);
        tw[TW1280_OFF + idx] = make_float2((float)cos(a), (float)sin(a));
    }
    if (idx < 944) {
        double a = -TWO_PI * ((double)idx / 944.0);
        tw[TW944_OFF + idx] = make_float2((float)cos(a), (float)sin(a));
    }
    if (idx < 4097) {
        float z = fminf((float)idx * (1.0f / (float)KBN), 1.0f);
        kbt[idx] = i0f_dev(BETA * sqrtf(z));
    }
    if (idx < IH) {
        float xi = (float)(idx - IH / 2) * (1.0f / (float)GH);
        float px = (float)(M_PI * (double)JW) * xi;
        float sxr = sqrtf(B2 - px * px);
        float ax = (float)JW * sinhf(sxr) / sxr;
        axt[idx] = SCALE / ax;
    }
    if (idx < IW) {
        float yj = (float)(idx - IW / 2) * (1.0f / (float)GW);
        float py = (float)(M_PI * (double)JW) * yj;
        float syr = sqrtf(B2 - py * py);
        float ay = (float)JW * sinhf(syr) / syr;
        ayt[idx] = 1.0f / ay;
    }
    if (idx < NBKT) hist[idx] = 0;
}

// ---------------------------------------------------------------------------
// Sort kernel 1: per-point bucket id + histogram
// bucket = b*160 + (m0>>6)*8 + (aw>>7)   (tile ~64 rows x 128 cols)
// ---------------------------------------------------------------------------
__global__ __launch_bounds__(256) void count_kernel(
        const float* __restrict__ ktraj, int* __restrict__ hist,
        int* __restrict__ bkt)
{
    int idx = blockIdx.x * 256 + threadIdx.x;
    if (idx >= BATCH * NK) return;
    int b = idx / NK;
    int k = idx % NK;
    const float sx = (float)((double)GH / (2.0 * M_PI));
    const float sy = (float)((double)GW / (2.0 * M_PI));
    float t0 = ktraj[(size_t)(b * 2 + 0) * NK + k] * sx;
    float t1 = ktraj[(size_t)(b * 2 + 1) * NK + k] * sy;
    int base0 = (int)floorf(t0);
    int m0 = base0 % GH; if (m0 < 0) m0 += GH;
    int j0u = (int)floorf(t1) - 2;
    int a0u = j0u & ~3;
    int aw = a0u; if (aw < 0) aw += GW;
    int bucket = b * 160 + (m0 >> 6) * 8 + (aw >> 7);
    bkt[idx] = bucket;
    atomicAdd(&hist[bucket], 1);
}

// ---------------------------------------------------------------------------
// Sort kernel 2: exclusive prefix over 640 buckets (one wave, shfl scan)
// ---------------------------------------------------------------------------
__global__ __launch_bounds__(64) void prefix_kernel(
        const int* __restrict__ hist, int* __restrict__ curs)
{
    int lane = threadIdx.x;               // 64 lanes x 10 buckets = 640
    int base = lane * 10;
    int loc[10];
    int s = 0;
    #pragma unroll
    for (int j = 0; j < 10; ++j) { loc[j] = s; s += hist[base + j]; }
    int acc = s;
    #pragma unroll
    for (int off = 1; off < 64; off <<= 1) {
        int n = __shfl_up(acc, off);
        if (lane >= off) acc += n;
    }
    int excl = acc - s;
    #pragma unroll
    for (int j = 0; j < 10; ++j) curs[base + j] = excl + loc[j];
}

// ---------------------------------------------------------------------------
// Sort kernel 3: scatter point indices into sorted order
// ---------------------------------------------------------------------------
__global__ __launch_bounds__(256) void scatter_kernel(
        const int* __restrict__ bkt, int* __restrict__ curs,
        int* __restrict__ perm)
{
    int idx = blockIdx.x * 256 + threadIdx.x;
    if (idx >= BATCH * NK) return;
    int bu = bkt[idx];
    int pos = atomicAdd(&curs[bu], 1);
    perm[pos] = idx;
}

// ---------------------------------------------------------------------------
// Kernel 1: FUSED apodize+pad+ifftshift+scale + 944-pt row FFT. 4 rows/block.
// ---------------------------------------------------------------------------
__global__ __launch_bounds__(256) void fft_row_kernel(
        const float* __restrict__ ir, const float* __restrict__ ii,
        unsigned int* __restrict__ gridh, const v2f* __restrict__ twg,
        const float* __restrict__ axt, const float* __restrict__ ayt,
        int b0, int nb)
{
    __shared__ v2f buf[4 * 948];

    int blk  = blockIdx.x;
    int lb   = blk / 160;
    int rblk = (blk % 160) * 4;
    int b    = b0 + lb;
    int tid  = threadIdx.x;
    const v2f* tw = twg + TW944_OFF;

    for (int item = tid; item < 4 * 944; item += 256) {
        int v  = item % 944;
        int rr = item / 944;
        int ri = rblk + rr;
        int i  = (ri < 320) ? ri + 320 : ri - 320;
        v2f val = (v2f){0.f, 0.f};
        int j = -1;
        if (v < (GW - IW) / 2) j = v + IW / 2;
        else if (v >= (GW + IW) / 2) j = v - (GW + IW) / 2;
        if (j >= 0) {
            float invA = axt[i] * ayt[j];
            size_t src = ((size_t)(b * IH + i)) * IW + j;
            val.x = ir[src] * invA;
            val.y = ii[src] * invA;
        }
        buf[rr * 948 + v] = val;
    }
    __syncthreads();

    if (tid < 236) {
        int r  = tid / 59;
        int k1 = tid % 59;
        int ri = rblk + r;
        int u  = (ri < 320) ? ri : ri + 640;
        unsigned int* rowp = gridh + ((size_t)(lb * GH + u)) * GWP;
        const v2f* bufr = buf + r * 948;

        v2f acc[16];
        #pragma unroll
        for (int n2 = 0; n2 < 16; ++n2) acc[n2] = (v2f){0.f, 0.f};

        v2f r59 = tw[16 * k1];
        v2f r59p = perp(r59);
        v2f w = (v2f){1.f, 0.f};
        v2f wp = (v2f){0.f, 1.f};
        for (int n1 = 0; n1 < 15; ++n1) {
            const v4f* pb = (const v4f*)(bufr + (n1 << 4));
            #pragma unroll
            for (int t4 = 0; t4 < 8; ++t4) {
                v4f q = pb[t4];
                v2f c0 = __builtin_shufflevector(q, q, 0, 1);
                v2f c1 = __builtin_shufflevector(q, q, 2, 3);
                cmacp(acc[2 * t4],     c0, w, wp);
                cmacp(acc[2 * t4 + 1], c1, w, wp);
            }
            w = cmulp(w, r59, r59p);
            wp = perp(w);
        }
        w = tw[16 * ((44 * k1) % 59)];
        wp = perp(w);
        for (int n1 = 44; n1 < 59; ++n1) {
            const v4f* pb = (const v4f*)(bufr + (n1 << 4));
            #pragma unroll
            for (int t4 = 0; t4 < 8; ++t4) {
                v4f q = pb[t4];
                v2f c0 = __builtin_shufflevector(q, q, 0, 1);
                v2f c1 = __builtin_shufflevector(q, q, 2, 3);
                cmacp(acc[2 * t4],     c0, w, wp);
                cmacp(acc[2 * t4 + 1], c1, w, wp);
            }
            w = cmulp(w, r59, r59p);
            wp = perp(w);
        }

        v2f tstep = tw[k1];
        v2f tstepp = perp(tstep);
        v2f t = (v2f){1.f, 0.f};
        v2f tp = (v2f){0.f, 1.f};
        #pragma unroll
        for (int n2 = 0; n2 < 16; ++n2) {
            acc[n2] = cmulp(acc[n2], t, tp);
            t = cmulp(t, tstep, tstepp);
            tp = perp(t);
        }

        v2f X[16];
        dft16(acc, X);
        #pragma unroll
        for (int q = 0; q < 16; ++q)
            rowp[k1 + 59 * q] = packbf(X[q]);
    }
}

// ---------------------------------------------------------------------------
// Kernel 2: 1280-pt column FFT (20*8*8), 4 cols/block, IN-PLACE packed bf16.
// ---------------------------------------------------------------------------
__global__ __launch_bounds__(256) void fft_col_kernel(
        unsigned int* __restrict__ gridh, const v2f* __restrict__ twg)
{
    __shared__ v2f buf[1280 * NC];

    int blk = blockIdx.x;
    int lb = blk / (GW / NC);
    int vb = blk % (GW / NC);
    unsigned int* baseh = gridh + (size_t)lb * GH * GWP + vb * NC;
    int tid = threadIdx.x;
    const v2f* tw = twg + TW1280_OFF;

    #pragma unroll
    for (int it = 0; it < 10; ++it) {
        int item = it * 256 + tid;
        int c  = item & (NC - 1);
        int up = item >> 2;
        int u  = (up < 320) ? up : up + 640;
        buf[up * NC + c] = unpackbf(baseh[(size_t)u * GWP + c]);
    }
    __syncthreads();

    // ---- stage A: thread (m,c), taps in registers, CT 20 = 4x5
    {
        int c = tid & 3;
        int m = tid >> 2;
        v2f x[10];
        #pragma unroll
        for (int n = 0; n < 10; ++n)
            x[n] = buf[(n * 64 + m) * NC + c];
        __syncthreads();

        v2f A[5][4];
        #pragma unroll
        for (int bq = 0; bq < 5; ++bq) {
            v2f x0 = x[bq], x3 = x[5 + bq];
            v2f ix3 = (v2f){-x3.y, x3.x};
            A[bq][0] = x0 + x3;
            A[bq][1] = x0 + ix3;
            A[bq][2] = x0 - x3;
            A[bq][3] = x0 - ix3;
        }
        const v2f T1  = (v2f){ 0.95105651629515353f, -0.30901699437494742f};
        const v2f T2  = (v2f){ 0.80901699437494742f, -0.58778525229247312f};
        const v2f T3  = (v2f){ 0.58778525229247312f, -0.80901699437494742f};
        const v2f T4  = (v2f){ 0.30901699437494742f, -0.95105651629515353f};
        const v2f T6  = (v2f){-0.30901699437494742f, -0.95105651629515353f};
        const v2f T8  = (v2f){-0.80901699437494742f, -0.58778525229247312f};
        const v2f T9  = (v2f){-0.95105651629515353f, -0.30901699437494742f};
        const v2f T12 = (v2f){-0.80901699437494742f,  0.58778525229247312f};
        A[1][1] = cmul(A[1][1], T1);  A[2][1] = cmul(A[2][1], T2);
        A[3][1] = cmul(A[3][1], T3);  A[4][1] = cmul(A[4][1], T4);
        A[1][2] = cmul(A[1][2], T2);  A[2][2] = cmul(A[2][2], T4);
        A[3][2] = cmul(A[3][2], T6);  A[4][2] = cmul(A[4][2], T8);
        A[1][3] = cmul(A[1][3], T3);  A[2][3] = cmul(A[2][3], T6);
        A[3][3] = cmul(A[3][3], T9);  A[4][3] = cmul(A[4][3], T12);

        v2f wstep = tw[4 * m];
        v2f wstepp = perp(wstep);
        #pragma unroll
        for (int ka = 0; ka < 4; ++ka) {
            v2f Y[5];
            dft5(A[0][ka], A[1][ka], A[2][ka], A[3][ka], A[4][ka], Y);
            v2f w = (ka == 0) ? (v2f){1.f, 0.f} : tw[m * ka];
            #pragma unroll
            for (int kb = 0; kb < 5; ++kb) {
                int k1 = ka + 4 * kb;
                v2f outv = cmulp(Y[kb], w, perp(w));
                buf[(m * 20 + (k1 ^ (m & 3))) * NC + c] = outv;
                w = cmulp(w, wstep, wstepp);
            }
        }
    }
    __syncthreads();

    // ---- stage B
    v2f T[3][8];
    #pragma unroll
    for (int ch = 0; ch < 3; ++ch) {
        int item = ch * 256 + tid;
        if (item < 640) {
            int c  = item & 3;
            int tt = item >> 2;
            int k1 = tt % 20;
            int m2 = tt / 20;

            v2f bb[8];
            #pragma unroll
            for (int m1 = 0; m1 < 8; ++m1) {
                int m = (m1 << 3) + m2;
                bb[m1] = buf[(m * 20 + (k1 ^ (m2 & 3))) * NC + c];
            }
            dft8(bb, T[ch]);

            v2f wb = tw[20 * m2];
            v2f wbp = perp(wb);
            v2f v = (v2f){1.f, 0.f};
            #pragma unroll
            for (int k21 = 0; k21 < 8; ++k21) {
                T[ch][k21] = cmulp(T[ch][k21], v, perp(v));
                v = cmulp(v, wb, wbp);
            }
        }
    }
    __syncthreads();

    #pragma unroll
    for (int ch = 0; ch < 3; ++ch) {
        int item = ch * 256 + tid;
        if (item < 640) {
            int c  = item & 3;
            int tt = item >> 2;
            int k1 = tt % 20;
            int m2 = tt / 20;
            #pragma unroll
            for (int k21 = 0; k21 < 8; ++k21)
                buf[(((k21 << 3) + m2) * 20 + k1) * NC + c] = T[ch][k21];
        }
    }
    __syncthreads();

    // ---- stage C
    #pragma unroll
    for (int ch = 0; ch < 3; ++ch) {
        int item = ch * 256 + tid;
        if (item < 640) {
            int c   = item & 3;
            int tt  = item >> 2;
            int k1  = tt % 20;
            int k21 = tt / 20;
            v2f bb[8];
            #pragma unroll
            for (int m2 = 0; m2 < 8; ++m2)
                bb[m2] = buf[(((k21 << 3) + m2) * 20 + k1) * NC + c];
            v2f X[8];
            dft8(bb, X);
            #pragma unroll
            for (int k22 = 0; k22 < 8; ++k22) {
                int rrow = k1 + 20 * k21 + 160 * k22;
                unsigned int pk = packbf(X[k22]);
                baseh[(size_t)rrow * GWP + c] = pk;
                if (vb < 2) baseh[(size_t)rrow * GWP + GW + c] = pk;
            }
        }
    }
}

// ---------------------------------------------------------------------------
// interp core (one point)
// ---------------------------------------------------------------------------
static __device__ __forceinline__ v2f interp_point(
        const float* kt, const unsigned int* gridh, int lb, float t0, float t1)
{
    int base0 = (int)floorf(t0);
    int base1 = (int)floorf(t1);

    int   ix[JW];
    float wx[JW];
    #pragma unroll
    for (int j = 0; j < JW; ++j) {
        int kx = base0 + j - (JW / 2 - 1);
        float u = t0 - (float)kx;
        float q = u * (1.0f / 3.0f);
        wx[j] = kbw(kt, 1.0f - q * q);
        int m = kx % GH; if (m < 0) m += GH;
        ix[j] = m;
    }
    int j0u = base1 - 2;
    int a0u = j0u & ~3;
    int aw = a0u; if (aw < 0) aw += GW;
    bool need3 = ((j0u & 3) == 3);
    float wy12[12];
    #pragma unroll
    for (int t = 0; t < 12; ++t) {
        float u = t1 - (float)(a0u + t);
        float q = u * (1.0f / 3.0f);
        wy12[t] = kbw(kt, 1.0f - q * q);
    }

    v2f acc = (v2f){0.f, 0.f};
    #pragma unroll
    for (int a = 0; a < JW; ++a) {
        const uint4* p4 = (const uint4*)(gridh +
            ((size_t)(lb * GH + ix[a])) * GWP + aw);
        uint4 q0 = p4[0];
        uint4 q1 = p4[1];
        uint4 q2 = need3 ? p4[2] : make_uint4(0u, 0u, 0u, 0u);
        unsigned int qs[12] = {q0.x, q0.y, q0.z, q0.w, q1.x, q1.y, q1.z, q1.w,
                               q2.x, q2.y, q2.z, q2.w};
        v2f rr = (v2f){0.f, 0.f};
        #pragma unroll
        for (int t = 0; t < 12; ++t)
            rr += wy12[t] * unpackbf(qs[t]);
        acc += wx[a] * rr;
    }
    return acc;
}

// ---------------------------------------------------------------------------
// Kernel 3a: KB interpolation in SORTED order (all 4 batches in grid)
// ---------------------------------------------------------------------------
__global__ __launch_bounds__(256) void interp_sorted_kernel(
        const float* __restrict__ ktraj, const unsigned int* __restrict__ gridh,
        const float* __restrict__ kbt, const int* __restrict__ perm,
        float* __restrict__ out, int write_complex)
{
    __shared__ float kt[4097];
    for (int t = threadIdx.x; t < 4097; t += 256) kt[t] = kbt[t];
    __syncthreads();

    int sidx = blockIdx.x * 256 + threadIdx.x;
    if (sidx >= BATCH * NK) return;
    int idx = perm[sidx];
    int b = idx / NK;
    int k = idx % NK;

    const float sx = (float)((double)GH / (2.0 * M_PI));
    const float sy = (float)((double)GW / (2.0 * M_PI));
    float t0 = ktraj[(size_t)(b * 2 + 0) * NK + k] * sx;
    float t1 = ktraj[(size_t)(b * 2 + 1) * NK + k] * sy;

    v2f acc = interp_point(kt, gridh, b, t0, t1);

    size_t p = (size_t)b * NK + k;
    if (write_complex) {
        ((float2*)out)[p] = make_float2(acc.x, acc.y);
    } else {
        out[p] = acc.x;
    }
}

// ---------------------------------------------------------------------------
// Kernel 3b: unsorted fallback (ws too small for sort scratch)
// ---------------------------------------------------------------------------
__global__ __launch_bounds__(256) void interp_kernel(
        const float* __restrict__ ktraj, const unsigned int* __restrict__ gridh,
        const float* __restrict__ kbt,
        float* __restrict__ out, int b0, int nb, int write_complex)
{
    __shared__ float kt[4097];
    for (int t = threadIdx.x; t < 4097; t += 256) kt[t] = kbt[t];
    __syncthreads();

    int idx = blockIdx.x * 256 + threadIdx.x;
    if (idx >= nb * NK) return;
    int lb = idx / NK;
    int k  = idx % NK;
    int b  = b0 + lb;

    const float sx = (float)((double)GH / (2.0 * M_PI));
    const float sy = (float)((double)GW / (2.0 * M_PI));
    float t0 = ktraj[(size_t)(b * 2 + 0) * NK + k] * sx;
    float t1 = ktraj[(size_t)(b * 2 + 1) * NK + k] * sy;

    v2f acc = interp_point(kt, gridh, lb, t0, t1);

    size_t p = (size_t)b * NK + k;
    if (write_complex) {
        ((float2*)out)[p] = make_float2(acc.x, acc.y);
    } else {
        out[p] = acc.x;
    }
}

// ---------------------------------------------------------------------------
extern "C" void kernel_launch(void* const* d_in, const int* in_sizes, int n_in,
                              void* d_out, int out_size, void* d_ws, size_t ws_size,
                              hipStream_t stream)
{
    const float* ir = (const float*)d_in[0];   // [B,640,472,1] float32
    const float* ii = (const float*)d_in[1];   // [B,640,472,1] float32
    const float* kt = (const float*)d_in[2];   // [B,2,K] float32
    float2* tw   = (float2*)d_ws;
    float*  kbt  = (float*)((char*)d_ws + KB_OFF_B);
    float*  axt  = (float*)((char*)d_ws + AX_OFF_B);
    float*  ayt  = (float*)((char*)d_ws + AY_OFF_B);
    float*  out  = (float*)d_out;

    int write_complex = (out_size >= 2 * BATCH * NK) ? 1 : 0;

    const size_t pb16 = (size_t)GH * GWP * sizeof(unsigned int); // 4.87 MB
    size_t avail = (ws_size > TW_RESERVE_BYTES) ? ws_size - TW_RESERVE_BYTES : 0;
    int nb = 1;
    if (avail >= 4 * pb16)      nb = 4;
    else if (avail >= 2 * pb16) nb = 2;

    unsigned int* gridh = (unsigned int*)((char*)d_ws + TW_RESERVE_BYTES);
    int use_sort = (nb == 4 && ws_size >= (size_t)SORT_END_B) ? 1 : 0;
    int* hist = (int*)((char*)d_ws + HIST_OFF_B);
    int* curs = (int*)((char*)d_ws + CURS_OFF_B);
    int* bkt  = (int*)((char*)d_ws + BKT_OFF_B);
    int* perm = (int*)((char*)d_ws + PERM_OFF_B);

    setup_kernel<<<17, 256, 0, stream>>>(tw, kbt, axt, ayt, hist);

    if (use_sort) {
        int npts = BATCH * NK;
        count_kernel<<<(npts + 255) / 256, 256, 0, stream>>>(kt, hist, bkt);
        prefix_kernel<<<1, 64, 0, stream>>>(hist, curs);
        scatter_kernel<<<(npts + 255) / 256, 256, 0, stream>>>(bkt, curs, perm);

        fft_row_kernel<<<4 * 160, 256, 0, stream>>>(ir, ii, gridh, (const v2f*)tw, axt, ayt, 0, 4);
        fft_col_kernel<<<4 * (GW / NC), 256, 0, stream>>>(gridh, (const v2f*)tw);
        interp_sorted_kernel<<<(npts + 255) / 256, 256, 0, stream>>>(kt, gridh, kbt, perm, out, write_complex);
    } else {
        for (int b0 = 0; b0 < BATCH; b0 += nb) {
            fft_row_kernel<<<nb * 160, 256, 0, stream>>>(ir, ii, gridh, (const v2f*)tw, axt, ayt, b0, nb);
            fft_col_kernel<<<nb * (GW / NC), 256, 0, stream>>>(gridh, (const v2f*)tw);
            interp_kernel<<<(nb * NK + 255) / 256, 256, 0, stream>>>(kt, gridh, kbt, out, b0, nb, write_complex);
        }
    }
}

// Round 18
// 218.682 us; speedup vs baseline: 1.5064x; 1.5064x over previous
//
#include <hip/hip_runtime.h>
#include <math.h>

// Problem constants (match reference)
#define BATCH 4
#define NK    100000
#define IH    640
#define IW    472
#define GH    1280          // oversampled grid rows = 2*IH   (1280 = 20*8*8)
#define GW    944           // oversampled grid cols = 2*IW   (944  = 59*16)
#define GWP   952           // padded row stride: 8 echo cols (window reach <= 951)
#define JW    6             // KB kernel width

// ws layout (bytes)
#define TW1280_OFF 0
#define TW944_OFF  1280
#define KB_OFF_B   18432
#define AX_OFF_B   34944
#define AY_OFF_B   37504
#define TW_RESERVE_BYTES 65536

#define KBN 4095
#define NC 4

// ---- sort constants (atomic-free counting sort) ----
#define NPTS   (BATCH * NK)            // 400000
#define NBLK   1563                    // ceil(NPTS/256)
#define NB     80                      // buckets: (b*2+half)*10 + subtile
#define RSTRIDE 200
#define NIBLK  (8 * RSTRIDE)           // interp blocks (8 XCD regions)

#define BLKCNT_OFF_B (32u * 1024 * 1024)            // NB*NBLK ints = 500160 B
#define OFFM_OFF_B   (BLKCNT_OFF_B + 512u * 1024)
#define BST_OFF_B    (OFFM_OFF_B + 512u * 1024)     // 81 ints
#define SREC_OFF_B   (BST_OFF_B + 4096)             // NPTS float4 = 6.4 MB
#define SORT_END_B   (SREC_OFF_B + 6406144)

typedef float v2f __attribute__((ext_vector_type(2)));
typedef float v4f __attribute__((ext_vector_type(4)));

static __device__ __forceinline__ float beta_f() {
    return (float)(M_PI * 4.410215414239989);   // pi*sqrt(19.45)
}

static __device__ __forceinline__ float i0f_dev(float x) {
    if (x < 3.75f) {
        float t = x * (1.0f / 3.75f);
        t *= t;
        return 1.0f + t*(3.5156229f + t*(3.0899424f + t*(1.2067492f +
               t*(0.2659732f + t*(0.0360768f + t*0.0045813f)))));
    } else {
        float t = 3.75f / x;
        float p = 0.39894228f + t*(0.01328592f + t*(0.00225319f + t*(-0.00157565f +
                  t*(0.00916281f + t*(-0.02057706f + t*(0.02635537f +
                  t*(-0.01647633f + t*0.00392377f)))))));
        return p * expf(x) / sqrtf(x);
    }
}

// ---- packed complex helpers
static __device__ __forceinline__ v2f perp(v2f w) { return (v2f){-w.y, w.x}; }
static __device__ __forceinline__ v2f cmulp(v2f x, v2f w, v2f wp) {
    v2f xr = __builtin_shufflevector(x, x, 0, 0);
    v2f xi = __builtin_shufflevector(x, x, 1, 1);
    return xr * w + xi * wp;
}
static __device__ __forceinline__ v2f cmul(v2f a, v2f b) { return cmulp(a, b, perp(b)); }
static __device__ __forceinline__ void cmacp(v2f& acc, v2f x, v2f w, v2f wp) {
    v2f xr = __builtin_shufflevector(x, x, 0, 0);
    v2f xi = __builtin_shufflevector(x, x, 1, 1);
    acc += xr * w;
    acc += xi * wp;
}

static __device__ __forceinline__ unsigned int f2bf(float f) {
    unsigned int u = __float_as_uint(f);
    return (u + 0x7FFFu + ((u >> 16) & 1u)) >> 16;
}
static __device__ __forceinline__ unsigned int packbf(v2f v) {
    return f2bf(v.x) | (f2bf(v.y) << 16);
}
static __device__ __forceinline__ v2f unpackbf(unsigned int p) {
    return (v2f){__uint_as_float(p << 16), __uint_as_float(p & 0xFFFF0000u)};
}

static __device__ __forceinline__ void dft4(v2f a0, v2f a1, v2f a2, v2f a3,
                                            v2f& o0, v2f& o1, v2f& o2, v2f& o3)
{
    v2f t0 = a0 + a2, t1 = a0 - a2;
    v2f t2 = a1 + a3, t3 = a1 - a3;
    o0 = t0 + t2;
    o2 = t0 - t2;
    v2f nit3 = (v2f){t3.y, -t3.x};
    o1 = t1 + nit3;
    o3 = t1 - nit3;
}

static __device__ __forceinline__ void dft8(const v2f* b, v2f* X)
{
    v2f e0, e1, e2, e3, o0, o1, o2, o3;
    dft4(b[0], b[2], b[4], b[6], e0, e1, e2, e3);
    dft4(b[1], b[3], b[5], b[7], o0, o1, o2, o3);
    const float C = 0.70710678118654752f;
    v2f m1 = cmulp(o1, (v2f){ C, -C}, (v2f){C,  C});
    v2f m2 = (v2f){o2.y, -o2.x};
    v2f m3 = cmulp(o3, (v2f){-C, -C}, (v2f){C, -C});
    X[0] = e0 + o0; X[4] = e0 - o0;
    X[1] = e1 + m1; X[5] = e1 - m1;
    X[2] = e2 + m2; X[6] = e2 - m2;
    X[3] = e3 + m3; X[7] = e3 - m3;
}

static __device__ __forceinline__ void dft5(v2f a0, v2f a1, v2f a2, v2f a3, v2f a4,
                                            v2f* X)
{
    const float c1 = 0.30901699437494742f, s1 = 0.95105651629515353f;
    const float c2 = -0.80901699437494742f, s2 = 0.58778525229247312f;
    v2f t1 = a1 + a4, d1 = a1 - a4;
    v2f t2 = a2 + a3, d2 = a2 - a3;
    X[0] = a0 + t1 + t2;
    v2f e1 = a0 + c1 * t1 + c2 * t2;
    v2f o1 = s1 * d1 + s2 * d2;
    v2f e2 = a0 + c2 * t1 + c1 * t2;
    v2f o2 = s2 * d1 - s1 * d2;
    X[1] = (v2f){e1.x + o1.y, e1.y - o1.x};
    X[4] = (v2f){e1.x - o1.y, e1.y + o1.x};
    X[2] = (v2f){e2.x + o2.y, e2.y - o2.x};
    X[3] = (v2f){e2.x - o2.y, e2.y + o2.x};
}

static __device__ __forceinline__ void dft16(const v2f* a, v2f* X)
{
    v2f y[4][4];
    #pragma unroll
    for (int n2 = 0; n2 < 4; ++n2)
        dft4(a[n2], a[4 + n2], a[8 + n2], a[12 + n2],
             y[n2][0], y[n2][1], y[n2][2], y[n2][3]);
    const float C  = 0.70710678118654752f;
    const float c1 = 0.92387953251128676f, s1 = 0.38268343236508977f;
    y[1][1] = cmulp(y[1][1], (v2f){ c1, -s1}, (v2f){ s1,  c1});
    y[1][2] = cmulp(y[1][2], (v2f){  C,  -C}, (v2f){  C,   C});
    y[1][3] = cmulp(y[1][3], (v2f){ s1, -c1}, (v2f){ c1,  s1});
    y[2][1] = cmulp(y[2][1], (v2f){  C,  -C}, (v2f){  C,   C});
    y[2][2] = (v2f){y[2][2].y, -y[2][2].x};
    y[2][3] = cmulp(y[2][3], (v2f){ -C,  -C}, (v2f){  C,  -C});
    y[3][1] = cmulp(y[3][1], (v2f){ s1, -c1}, (v2f){ c1,  s1});
    y[3][2] = cmulp(y[3][2], (v2f){ -C,  -C}, (v2f){  C,  -C});
    y[3][3] = cmulp(y[3][3], (v2f){-c1,  s1}, (v2f){-s1, -c1});
    #pragma unroll
    for (int k1 = 0; k1 < 4; ++k1)
        dft4(y[0][k1], y[1][k1], y[2][k1], y[3][k1],
             X[k1], X[k1 + 4], X[k1 + 8], X[k1 + 12]);
}

static __device__ __forceinline__ float kbw(const float* kt, float zz) {
    float t = fmaxf(zz * (float)KBN, 0.0f);
    int i = (int)t;
    float fr = t - (float)i;
    float w = fmaf(fr, kt[i + 1] - kt[i], kt[i]);
    return (zz > 0.f) ? w : 0.f;
}

// bucket from trajectory (must be identical in count & scatter)
static __device__ __forceinline__ int bucket_of(int b, float t0) {
    int base0 = (int)floorf(t0);
    int m0 = base0 % GH; if (m0 < 0) m0 += GH;
    int half = (m0 >= 640) ? 1 : 0;
    int sub = (m0 - half * 640) >> 6;          // 0..9
    return (b * 2 + half) * 10 + sub;          // 0..79
}

// ---------------------------------------------------------------------------
// Kernel 0: setup — twiddles + KB weight table + apodization tables
// ---------------------------------------------------------------------------
__global__ __launch_bounds__(256) void setup_kernel(
        float2* __restrict__ tw, float* __restrict__ kbt,
        float* __restrict__ axt, float* __restrict__ ayt)
{
    int idx = blockIdx.x * 256 + threadIdx.x;
    const double TWO_PI = 6.283185307179586476925286766559;
    const float BETA = beta_f();
    const float B2 = (float)(M_PI * M_PI * 19.45);
    const float SCALE = (float)(1.0 / 1099.236098591787);

    if (idx < 1280) {
        double a = -TWO_PI * ((double)idx / 1280.0);
        tw[TW1280_OFF + idx] = make_float2((float)cos(a), (float)sin(a));
    }
    if (idx < 944) {
        double a = -TWO_PI * ((double)idx / 944.0);
        tw[TW944_OFF + idx] = make_float2((float)cos(a), (float)sin(a));
    }
    if (idx < 4097) {
        float z = fminf((float)idx * (1.0f / (float)KBN), 1.0f);
        kbt[idx] = i0f_dev(BETA * sqrtf(z));
    }
    if (idx < IH) {
        float xi = (float)(idx - IH / 2) * (1.0f / (float)GH);
        float px = (float)(M_PI * (double)JW) * xi;
        float sxr = sqrtf(B2 - px * px);
        float ax = (float)JW * sinhf(sxr) / sxr;
        axt[idx] = SCALE / ax;
    }
    if (idx < IW) {
        float yj = (float)(idx - IW / 2) * (1.0f / (float)GW);
        float py = (float)(M_PI * (double)JW) * yj;
        float syr = sqrtf(B2 - py * py);
        float ay = (float)JW * sinhf(syr) / syr;
        ayt[idx] = 1.0f / ay;
    }
}

// ---------------------------------------------------------------------------
// Sort 1: per-block LDS histogram -> blkcnt[bu][blk]   (NO global atomics)
// ---------------------------------------------------------------------------
__global__ __launch_bounds__(256) void count_kernel(
        const float* __restrict__ ktraj, int* __restrict__ blkcnt)
{
    __shared__ int lh[NB];
    int tid = threadIdx.x;
    int idx = blockIdx.x * 256 + tid;
    if (tid < NB) lh[tid] = 0;
    __syncthreads();
    if (idx < NPTS) {
        int b = idx / NK;
        int k = idx % NK;
        const float sx = (float)((double)GH / (2.0 * M_PI));
        float t0 = ktraj[(size_t)(b * 2 + 0) * NK + k] * sx;
        atomicAdd(&lh[bucket_of(b, t0)], 1);
    }
    __syncthreads();
    if (tid < NB) blkcnt[tid * NBLK + blockIdx.x] = lh[tid];
}

// ---------------------------------------------------------------------------
// Sort 2: column scans (one 1024-thread block; wave w scans buckets 5w..5w+4)
// offm[bu][blk] = exclusive prefix within bucket; bst[0..80] bucket starts.
// ---------------------------------------------------------------------------
__global__ __launch_bounds__(1024) void scan_kernel(
        const int* __restrict__ blkcnt, int* __restrict__ offm,
        int* __restrict__ bst_g)
{
    __shared__ int tots[NB];
    __shared__ int bst[NB + 1];
    int wave = threadIdx.x >> 6;
    int lane = threadIdx.x & 63;

    for (int q = 0; q < 5; ++q) {
        int bu = wave * 5 + q;
        int running = 0;
        for (int c = 0; c < (NBLK + 63) / 64; ++c) {
            int i = c * 64 + lane;
            int v = (i < NBLK) ? blkcnt[bu * NBLK + i] : 0;
            int incl = v;
            #pragma unroll
            for (int off = 1; off < 64; off <<= 1) {
                int n = __shfl_up(incl, off);
                if (lane >= off) incl += n;
            }
            if (i < NBLK) offm[bu * NBLK + i] = running + (incl - v);
            running += __shfl(incl, 63);
        }
        if (lane == 0) tots[bu] = running;
    }
    __syncthreads();
    if (threadIdx.x == 0) {
        int s = 0;
        for (int bu = 0; bu < NB; ++bu) { bst[bu] = s; s += tots[bu]; }
        bst[NB] = s;
    }
    __syncthreads();
    if (threadIdx.x < NB + 1) bst_g[threadIdx.x] = bst[threadIdx.x];
}

// ---------------------------------------------------------------------------
// Sort 3: scatter sorted records (t0, t1, idx) — LDS atomics only
// ---------------------------------------------------------------------------
__global__ __launch_bounds__(256) void scatter_kernel(
        const float* __restrict__ ktraj, const int* __restrict__ offm,
        const int* __restrict__ bst_g, float4* __restrict__ srec)
{
    __shared__ int lh[NB];
    __shared__ int lbase[NB];
    int tid = threadIdx.x;
    int idx = blockIdx.x * 256 + tid;
    if (tid < NB) lh[tid] = 0;
    __syncthreads();

    int bu = -1, rank = 0;
    float t0 = 0.f, t1 = 0.f;
    if (idx < NPTS) {
        int b = idx / NK;
        int k = idx % NK;
        const float sx = (float)((double)GH / (2.0 * M_PI));
        const float sy = (float)((double)GW / (2.0 * M_PI));
        t0 = ktraj[(size_t)(b * 2 + 0) * NK + k] * sx;
        t1 = ktraj[(size_t)(b * 2 + 1) * NK + k] * sy;
        bu = bucket_of(b, t0);
        rank = atomicAdd(&lh[bu], 1);
    }
    __syncthreads();
    if (tid < NB) lbase[tid] = bst_g[tid] + offm[tid * NBLK + blockIdx.x];
    __syncthreads();
    if (idx < NPTS) {
        int pos = lbase[bu] + rank;
        float4 r;
        r.x = t0; r.y = t1; r.z = __int_as_float(idx); r.w = 0.f;
        srec[pos] = r;
    }
}

// ---------------------------------------------------------------------------
// Kernel 1: FUSED apodize+pad+ifftshift+scale + 944-pt row FFT. 4 rows/block.
// ---------------------------------------------------------------------------
__global__ __launch_bounds__(256) void fft_row_kernel(
        const float* __restrict__ ir, const float* __restrict__ ii,
        unsigned int* __restrict__ gridh, const v2f* __restrict__ twg,
        const float* __restrict__ axt, const float* __restrict__ ayt,
        int b0, int nb)
{
    __shared__ v2f buf[4 * 948];

    int blk  = blockIdx.x;
    int lb   = blk / 160;
    int rblk = (blk % 160) * 4;
    int b    = b0 + lb;
    int tid  = threadIdx.x;
    const v2f* tw = twg + TW944_OFF;

    for (int item = tid; item < 4 * 944; item += 256) {
        int v  = item % 944;
        int rr = item / 944;
        int ri = rblk + rr;
        int i  = (ri < 320) ? ri + 320 : ri - 320;
        v2f val = (v2f){0.f, 0.f};
        int j = -1;
        if (v < (GW - IW) / 2) j = v + IW / 2;
        else if (v >= (GW + IW) / 2) j = v - (GW + IW) / 2;
        if (j >= 0) {
            float invA = axt[i] * ayt[j];
            size_t src = ((size_t)(b * IH + i)) * IW + j;
            val.x = ir[src] * invA;
            val.y = ii[src] * invA;
        }
        buf[rr * 948 + v] = val;
    }
    __syncthreads();

    if (tid < 236) {
        int r  = tid / 59;
        int k1 = tid % 59;
        int ri = rblk + r;
        int u  = (ri < 320) ? ri : ri + 640;
        unsigned int* rowp = gridh + ((size_t)(lb * GH + u)) * GWP;
        const v2f* bufr = buf + r * 948;

        v2f acc[16];
        #pragma unroll
        for (int n2 = 0; n2 < 16; ++n2) acc[n2] = (v2f){0.f, 0.f};

        v2f r59 = tw[16 * k1];
        v2f r59p = perp(r59);
        v2f w = (v2f){1.f, 0.f};
        v2f wp = (v2f){0.f, 1.f};
        for (int n1 = 0; n1 < 15; ++n1) {
            const v4f* pb = (const v4f*)(bufr + (n1 << 4));
            #pragma unroll
            for (int t4 = 0; t4 < 8; ++t4) {
                v4f q = pb[t4];
                v2f c0 = __builtin_shufflevector(q, q, 0, 1);
                v2f c1 = __builtin_shufflevector(q, q, 2, 3);
                cmacp(acc[2 * t4],     c0, w, wp);
                cmacp(acc[2 * t4 + 1], c1, w, wp);
            }
            w = cmulp(w, r59, r59p);
            wp = perp(w);
        }
        w = tw[16 * ((44 * k1) % 59)];
        wp = perp(w);
        for (int n1 = 44; n1 < 59; ++n1) {
            const v4f* pb = (const v4f*)(bufr + (n1 << 4));
            #pragma unroll
            for (int t4 = 0; t4 < 8; ++t4) {
                v4f q = pb[t4];
                v2f c0 = __builtin_shufflevector(q, q, 0, 1);
                v2f c1 = __builtin_shufflevector(q, q, 2, 3);
                cmacp(acc[2 * t4],     c0, w, wp);
                cmacp(acc[2 * t4 + 1], c1, w, wp);
            }
            w = cmulp(w, r59, r59p);
            wp = perp(w);
        }

        v2f tstep = tw[k1];
        v2f tstepp = perp(tstep);
        v2f t = (v2f){1.f, 0.f};
        v2f tp = (v2f){0.f, 1.f};
        #pragma unroll
        for (int n2 = 0; n2 < 16; ++n2) {
            acc[n2] = cmulp(acc[n2], t, tp);
            t = cmulp(t, tstep, tstepp);
            tp = perp(t);
        }

        v2f X[16];
        dft16(acc, X);
        #pragma unroll
        for (int q = 0; q < 16; ++q)
            rowp[k1 + 59 * q] = packbf(X[q]);
    }
}

// ---------------------------------------------------------------------------
// Kernel 2: 1280-pt column FFT (20*8*8), 4 cols/block, IN-PLACE packed bf16.
// ---------------------------------------------------------------------------
__global__ __launch_bounds__(256) void fft_col_kernel(
        unsigned int* __restrict__ gridh, const v2f* __restrict__ twg)
{
    __shared__ v2f buf[1280 * NC];

    int blk = blockIdx.x;
    int lb = blk / (GW / NC);
    int vb = blk % (GW / NC);
    unsigned int* baseh = gridh + (size_t)lb * GH * GWP + vb * NC;
    int tid = threadIdx.x;
    const v2f* tw = twg + TW1280_OFF;

    #pragma unroll
    for (int it = 0; it < 10; ++it) {
        int item = it * 256 + tid;
        int c  = item & (NC - 1);
        int up = item >> 2;
        int u  = (up < 320) ? up : up + 640;
        buf[up * NC + c] = unpackbf(baseh[(size_t)u * GWP + c]);
    }
    __syncthreads();

    // stage A: thread (m,c), taps in registers, CT 20 = 4x5
    {
        int c = tid & 3;
        int m = tid >> 2;
        v2f x[10];
        #pragma unroll
        for (int n = 0; n < 10; ++n)
            x[n] = buf[(n * 64 + m) * NC + c];
        __syncthreads();

        v2f A[5][4];
        #pragma unroll
        for (int bq = 0; bq < 5; ++bq) {
            v2f x0 = x[bq], x3 = x[5 + bq];
            v2f ix3 = (v2f){-x3.y, x3.x};
            A[bq][0] = x0 + x3;
            A[bq][1] = x0 + ix3;
            A[bq][2] = x0 - x3;
            A[bq][3] = x0 - ix3;
        }
        const v2f T1  = (v2f){ 0.95105651629515353f, -0.30901699437494742f};
        const v2f T2  = (v2f){ 0.80901699437494742f, -0.58778525229247312f};
        const v2f T3  = (v2f){ 0.58778525229247312f, -0.80901699437494742f};
        const v2f T4  = (v2f){ 0.30901699437494742f, -0.95105651629515353f};
        const v2f T6  = (v2f){-0.30901699437494742f, -0.95105651629515353f};
        const v2f T8  = (v2f){-0.80901699437494742f, -0.58778525229247312f};
        const v2f T9  = (v2f){-0.95105651629515353f, -0.30901699437494742f};
        const v2f T12 = (v2f){-0.80901699437494742f,  0.58778525229247312f};
        A[1][1] = cmul(A[1][1], T1);  A[2][1] = cmul(A[2][1], T2);
        A[3][1] = cmul(A[3][1], T3);  A[4][1] = cmul(A[4][1], T4);
        A[1][2] = cmul(A[1][2], T2);  A[2][2] = cmul(A[2][2], T4);
        A[3][2] = cmul(A[3][2], T6);  A[4][2] = cmul(A[4][2], T8);
        A[1][3] = cmul(A[1][3], T3);  A[2][3] = cmul(A[2][3], T6);
        A[3][3] = cmul(A[3][3], T9);  A[4][3] = cmul(A[4][3], T12);

        v2f wstep = tw[4 * m];
        v2f wstepp = perp(wstep);
        #pragma unroll
        for (int ka = 0; ka < 4; ++ka) {
            v2f Y[5];
            dft5(A[0][ka], A[1][ka], A[2][ka], A[3][ka], A[4][ka], Y);
            v2f w = (ka == 0) ? (v2f){1.f, 0.f} : tw[m * ka];
            #pragma unroll
            for (int kb = 0; kb < 5; ++kb) {
                int k1 = ka + 4 * kb;
                v2f outv = cmulp(Y[kb], w, perp(w));
                buf[(m * 20 + (k1 ^ (m & 3))) * NC + c] = outv;
                w = cmulp(w, wstep, wstepp);
            }
        }
    }
    __syncthreads();

    // stage B
    v2f T[3][8];
    #pragma unroll
    for (int ch = 0; ch < 3; ++ch) {
        int item = ch * 256 + tid;
        if (item < 640) {
            int c  = item & 3;
            int tt = item >> 2;
            int k1 = tt % 20;
            int m2 = tt / 20;

            v2f bb[8];
            #pragma unroll
            for (int m1 = 0; m1 < 8; ++m1) {
                int m = (m1 << 3) + m2;
                bb[m1] = buf[(m * 20 + (k1 ^ (m2 & 3))) * NC + c];
            }
            dft8(bb, T[ch]);

            v2f wb = tw[20 * m2];
            v2f wbp = perp(wb);
            v2f v = (v2f){1.f, 0.f};
            #pragma unroll
            for (int k21 = 0; k21 < 8; ++k21) {
                T[ch][k21] = cmulp(T[ch][k21], v, perp(v));
                v = cmulp(v, wb, wbp);
            }
        }
    }
    __syncthreads();

    #pragma unroll
    for (int ch = 0; ch < 3; ++ch) {
        int item = ch * 256 + tid;
        if (item < 640) {
            int c  = item & 3;
            int tt = item >> 2;
            int k1 = tt % 20;
            int m2 = tt / 20;
            #pragma unroll
            for (int k21 = 0; k21 < 8; ++k21)
                buf[(((k21 << 3) + m2) * 20 + k1) * NC + c] = T[ch][k21];
        }
    }
    __syncthreads();

    // stage C
    #pragma unroll
    for (int ch = 0; ch < 3; ++ch) {
        int item = ch * 256 + tid;
        if (item < 640) {
            int c   = item & 3;
            int tt  = item >> 2;
            int k1  = tt % 20;
            int k21 = tt / 20;
            v2f bb[8];
            #pragma unroll
            for (int m2 = 0; m2 < 8; ++m2)
                bb[m2] = buf[(((k21 << 3) + m2) * 20 + k1) * NC + c];
            v2f X[8];
            dft8(bb, X);
            #pragma unroll
            for (int k22 = 0; k22 < 8; ++k22) {
                int rrow = k1 + 20 * k21 + 160 * k22;
                unsigned int pk = packbf(X[k22]);
                baseh[(size_t)rrow * GWP + c] = pk;
                if (vb < 2) baseh[(size_t)rrow * GWP + GW + c] = pk;
            }
        }
    }
}

// ---------------------------------------------------------------------------
// interp core (one point)
// ---------------------------------------------------------------------------
static __device__ __forceinline__ v2f interp_point(
        const float* kt, const unsigned int* gridh, int lb, float t0, float t1)
{
    int base0 = (int)floorf(t0);
    int base1 = (int)floorf(t1);

    int   ix[JW];
    float wx[JW];
    #pragma unroll
    for (int j = 0; j < JW; ++j) {
        int kx = base0 + j - (JW / 2 - 1);
        float u = t0 - (float)kx;
        float q = u * (1.0f / 3.0f);
        wx[j] = kbw(kt, 1.0f - q * q);
        int m = kx % GH; if (m < 0) m += GH;
        ix[j] = m;
    }
    int j0u = base1 - 2;
    int a0u = j0u & ~3;
    int aw = a0u; if (aw < 0) aw += GW;
    bool need3 = ((j0u & 3) == 3);
    float wy12[12];
    #pragma unroll
    for (int t = 0; t < 12; ++t) {
        float u = t1 - (float)(a0u + t);
        float q = u * (1.0f / 3.0f);
        wy12[t] = kbw(kt, 1.0f - q * q);
    }

    v2f acc = (v2f){0.f, 0.f};
    #pragma unroll
    for (int a = 0; a < JW; ++a) {
        const uint4* p4 = (const uint4*)(gridh +
            ((size_t)(lb * GH + ix[a])) * GWP + aw);
        uint4 q0 = p4[0];
        uint4 q1 = p4[1];
        uint4 q2 = need3 ? p4[2] : make_uint4(0u, 0u, 0u, 0u);
        unsigned int qs[12] = {q0.x, q0.y, q0.z, q0.w, q1.x, q1.y, q1.z, q1.w,
                               q2.x, q2.y, q2.z, q2.w};
        v2f rr = (v2f){0.f, 0.f};
        #pragma unroll
        for (int t = 0; t < 12; ++t)
            rr += wy12[t] * unpackbf(qs[t]);
        acc += wx[a] * rr;
    }
    return acc;
}

// ---------------------------------------------------------------------------
// Kernel 3a: interp in sorted order. Region x = blockIdx&7 = (batch, rowhalf);
// each region's gather set is a 2.44 MB half-slab (fits one XCD L2).
// ---------------------------------------------------------------------------
__global__ __launch_bounds__(256) void interp_sorted_kernel(
        const unsigned int* __restrict__ gridh, const float* __restrict__ kbt,
        const float4* __restrict__ srec, const int* __restrict__ bst_g,
        float* __restrict__ out, int write_complex)
{
    int x = blockIdx.x & 7;
    int sbeg = bst_g[x * 10];
    int send = bst_g[(x + 1) * 10];
    int slot0 = blockIdx.x >> 3;
    if (sbeg + slot0 * 256 >= send) return;      // block-uniform early exit

    __shared__ float kt[4097];
    for (int t = threadIdx.x; t < 4097; t += 256) kt[t] = kbt[t];
    __syncthreads();

    for (int slot = slot0; sbeg + slot * 256 < send; slot += RSTRIDE) {
        int sidx = sbeg + slot * 256 + threadIdx.x;
        if (sidx < send) {
            float4 r = srec[sidx];
            float t0 = r.x, t1 = r.y;
            int idx = __float_as_int(r.z);
            int b = idx / NK;
            v2f acc = interp_point(kt, gridh, b, t0, t1);
            if (write_complex) {
                ((float2*)out)[idx] = make_float2(acc.x, acc.y);
            } else {
                out[idx] = acc.x;
            }
        }
    }
}

// ---------------------------------------------------------------------------
// Kernel 3b: unsorted fallback
// ---------------------------------------------------------------------------
__global__ __launch_bounds__(256) void interp_kernel(
        const float* __restrict__ ktraj, const unsigned int* __restrict__ gridh,
        const float* __restrict__ kbt,
        float* __restrict__ out, int b0, int nb, int write_complex)
{
    __shared__ float kt[4097];
    for (int t = threadIdx.x; t < 4097; t += 256) kt[t] = kbt[t];
    __syncthreads();

    int idx = blockIdx.x * 256 + threadIdx.x;
    if (idx >= nb * NK) return;
    int lb = idx / NK;
    int k  = idx % NK;
    int b  = b0 + lb;

    const float sx = (float)((double)GH / (2.0 * M_PI));
    const float sy = (float)((double)GW / (2.0 * M_PI));
    float t0 = ktraj[(size_t)(b * 2 + 0) * NK + k] * sx;
    float t1 = ktraj[(size_t)(b * 2 + 1) * NK + k] * sy;

    v2f acc = interp_point(kt, gridh, lb, t0, t1);

    size_t p = (size_t)b * NK + k;
    if (write_complex) {
        ((float2*)out)[p] = make_float2(acc.x, acc.y);
    } else {
        out[p] = acc.x;
    }
}

// ---------------------------------------------------------------------------
extern "C" void kernel_launch(void* const* d_in, const int* in_sizes, int n_in,
                              void* d_out, int out_size, void* d_ws, size_t ws_size,
                              hipStream_t stream)
{
    const float* ir = (const float*)d_in[0];   // [B,640,472,1] float32
    const float* ii = (const float*)d_in[1];   // [B,640,472,1] float32
    const float* kt = (const float*)d_in[2];   // [B,2,K] float32
    float2* tw   = (float2*)d_ws;
    float*  kbt  = (float*)((char*)d_ws + KB_OFF_B);
    float*  axt  = (float*)((char*)d_ws + AX_OFF_B);
    float*  ayt  = (float*)((char*)d_ws + AY_OFF_B);
    float*  out  = (float*)d_out;

    int write_complex = (out_size >= 2 * BATCH * NK) ? 1 : 0;

    const size_t pb16 = (size_t)GH * GWP * sizeof(unsigned int); // 4.87 MB
    size_t avail = (ws_size > TW_RESERVE_BYTES) ? ws_size - TW_RESERVE_BYTES : 0;
    int nb = 1;
    if (avail >= 4 * pb16)      nb = 4;
    else if (avail >= 2 * pb16) nb = 2;

    unsigned int* gridh = (unsigned int*)((char*)d_ws + TW_RESERVE_BYTES);
    int use_sort = (nb == 4 && ws_size >= (size_t)SORT_END_B) ? 1 : 0;
    int*    blkcnt = (int*)((char*)d_ws + BLKCNT_OFF_B);
    int*    offm   = (int*)((char*)d_ws + OFFM_OFF_B);
    int*    bstg   = (int*)((char*)d_ws + BST_OFF_B);
    float4* srec   = (float4*)((char*)d_ws + SREC_OFF_B);

    setup_kernel<<<17, 256, 0, stream>>>(tw, kbt, axt, ayt);

    if (use_sort) {
        count_kernel<<<NBLK, 256, 0, stream>>>(kt, blkcnt);
        scan_kernel<<<1, 1024, 0, stream>>>(blkcnt, offm, bstg);
        scatter_kernel<<<NBLK, 256, 0, stream>>>(kt, offm, bstg, srec);

        fft_row_kernel<<<4 * 160, 256, 0, stream>>>(ir, ii, gridh, (const v2f*)tw, axt, ayt, 0, 4);
        fft_col_kernel<<<4 * (GW / NC), 256, 0, stream>>>(gridh, (const v2f*)tw);
        interp_sorted_kernel<<<NIBLK, 256, 0, stream>>>(gridh, kbt, srec, bstg, out, write_complex);
    } else {
        for (int b0 = 0; b0 < BATCH; b0 += nb) {
            fft_row_kernel<<<nb * 160, 256, 0, stream>>>(ir, ii, gridh, (const v2f*)tw, axt, ayt, b0, nb);
            fft_col_kernel<<<nb * (GW / NC), 256, 0, stream>>>(gridh, (const v2f*)tw);
            interp_kernel<<<(nb * NK + 255) / 256, 256, 0, stream>>>(kt, gridh, kbt, out, b0, nb, write_complex);
        }
    }
}

// Round 19
// 159.106 us; speedup vs baseline: 2.0704x; 1.3744x over previous
//
#include <hip/hip_runtime.h>
#include <math.h>

// Problem constants (match reference)
#define BATCH 4
#define NK    100000
#define IH    640
#define IW    472
#define GH    1280          // oversampled grid rows = 2*IH   (1280 = 20*8*8)
#define GW    944           // oversampled grid cols = 2*IW   (944  = 59*16)
#define GWP   952           // padded row stride: 8 echo cols (window reach <= 951)
#define JW    6             // KB kernel width

// ws layout (bytes)
#define TW1280_OFF 0
#define TW944_OFF  1280
#define KB_OFF_B   18432
#define AX_OFF_B   34944
#define AY_OFF_B   37504
#define TW_RESERVE_BYTES 65536

#define KBN 4095
#define NC 4

// ---- sort constants (atomic-free counting sort) ----
#define NPTS   (BATCH * NK)            // 400000
#define CBLK   160                     // count/scatter blocks
#define PPB    2500                    // points per block (160*2500 = 400000)
#define NB     80                      // buckets: (b*2+half)*10 + subtile
#define RSTRIDE 200
#define NIBLK  (8 * RSTRIDE)           // interp blocks (8 XCD regions)

#define BLKCNT_OFF_B (32u * 1024 * 1024)            // NB*CBLK ints = 51200 B
#define OFFM_OFF_B   (BLKCNT_OFF_B + 64u * 1024)
#define BST_OFF_B    (OFFM_OFF_B + 64u * 1024)      // 81 ints
#define SREC_OFF_B   (BST_OFF_B + 4096)             // NPTS float4 = 6.4 MB
#define SORT_END_B   (SREC_OFF_B + 6406144)

typedef float v2f __attribute__((ext_vector_type(2)));
typedef float v4f __attribute__((ext_vector_type(4)));

static __device__ __forceinline__ float beta_f() {
    return (float)(M_PI * 4.410215414239989);   // pi*sqrt(19.45)
}

static __device__ __forceinline__ float i0f_dev(float x) {
    if (x < 3.75f) {
        float t = x * (1.0f / 3.75f);
        t *= t;
        return 1.0f + t*(3.5156229f + t*(3.0899424f + t*(1.2067492f +
               t*(0.2659732f + t*(0.0360768f + t*0.0045813f)))));
    } else {
        float t = 3.75f / x;
        float p = 0.39894228f + t*(0.01328592f + t*(0.00225319f + t*(-0.00157565f +
                  t*(0.00916281f + t*(-0.02057706f + t*(0.02635537f +
                  t*(-0.01647633f + t*0.00392377f)))))));
        return p * expf(x) / sqrtf(x);
    }
}

// ---- packed complex helpers
static __device__ __forceinline__ v2f perp(v2f w) { return (v2f){-w.y, w.x}; }
static __device__ __forceinline__ v2f cmulp(v2f x, v2f w, v2f wp) {
    v2f xr = __builtin_shufflevector(x, x, 0, 0);
    v2f xi = __builtin_shufflevector(x, x, 1, 1);
    return xr * w + xi * wp;
}
static __device__ __forceinline__ v2f cmul(v2f a, v2f b) { return cmulp(a, b, perp(b)); }
static __device__ __forceinline__ void cmacp(v2f& acc, v2f x, v2f w, v2f wp) {
    v2f xr = __builtin_shufflevector(x, x, 0, 0);
    v2f xi = __builtin_shufflevector(x, x, 1, 1);
    acc += xr * w;
    acc += xi * wp;
}

static __device__ __forceinline__ unsigned int f2bf(float f) {
    unsigned int u = __float_as_uint(f);
    return (u + 0x7FFFu + ((u >> 16) & 1u)) >> 16;
}
static __device__ __forceinline__ unsigned int packbf(v2f v) {
    return f2bf(v.x) | (f2bf(v.y) << 16);
}
static __device__ __forceinline__ v2f unpackbf(unsigned int p) {
    return (v2f){__uint_as_float(p << 16), __uint_as_float(p & 0xFFFF0000u)};
}

static __device__ __forceinline__ void dft4(v2f a0, v2f a1, v2f a2, v2f a3,
                                            v2f& o0, v2f& o1, v2f& o2, v2f& o3)
{
    v2f t0 = a0 + a2, t1 = a0 - a2;
    v2f t2 = a1 + a3, t3 = a1 - a3;
    o0 = t0 + t2;
    o2 = t0 - t2;
    v2f nit3 = (v2f){t3.y, -t3.x};
    o1 = t1 + nit3;
    o3 = t1 - nit3;
}

static __device__ __forceinline__ void dft8(const v2f* b, v2f* X)
{
    v2f e0, e1, e2, e3, o0, o1, o2, o3;
    dft4(b[0], b[2], b[4], b[6], e0, e1, e2, e3);
    dft4(b[1], b[3], b[5], b[7], o0, o1, o2, o3);
    const float C = 0.70710678118654752f;
    v2f m1 = cmulp(o1, (v2f){ C, -C}, (v2f){C,  C});
    v2f m2 = (v2f){o2.y, -o2.x};
    v2f m3 = cmulp(o3, (v2f){-C, -C}, (v2f){C, -C});
    X[0] = e0 + o0; X[4] = e0 - o0;
    X[1] = e1 + m1; X[5] = e1 - m1;
    X[2] = e2 + m2; X[6] = e2 - m2;
    X[3] = e3 + m3; X[7] = e3 - m3;
}

static __device__ __forceinline__ void dft5(v2f a0, v2f a1, v2f a2, v2f a3, v2f a4,
                                            v2f* X)
{
    const float c1 = 0.30901699437494742f, s1 = 0.95105651629515353f;
    const float c2 = -0.80901699437494742f, s2 = 0.58778525229247312f;
    v2f t1 = a1 + a4, d1 = a1 - a4;
    v2f t2 = a2 + a3, d2 = a2 - a3;
    X[0] = a0 + t1 + t2;
    v2f e1 = a0 + c1 * t1 + c2 * t2;
    v2f o1 = s1 * d1 + s2 * d2;
    v2f e2 = a0 + c2 * t1 + c1 * t2;
    v2f o2 = s2 * d1 - s1 * d2;
    X[1] = (v2f){e1.x + o1.y, e1.y - o1.x};
    X[4] = (v2f){e1.x - o1.y, e1.y + o1.x};
    X[2] = (v2f){e2.x + o2.y, e2.y - o2.x};
    X[3] = (v2f){e2.x - o2.y, e2.y + o2.x};
}

static __device__ __forceinline__ void dft16(const v2f* a, v2f* X)
{
    v2f y[4][4];
    #pragma unroll
    for (int n2 = 0; n2 < 4; ++n2)
        dft4(a[n2], a[4 + n2], a[8 + n2], a[12 + n2],
             y[n2][0], y[n2][1], y[n2][2], y[n2][3]);
    const float C  = 0.70710678118654752f;
    const float c1 = 0.92387953251128676f, s1 = 0.38268343236508977f;
    y[1][1] = cmulp(y[1][1], (v2f){ c1, -s1}, (v2f){ s1,  c1});
    y[1][2] = cmulp(y[1][2], (v2f){  C,  -C}, (v2f){  C,   C});
    y[1][3] = cmulp(y[1][3], (v2f){ s1, -c1}, (v2f){ c1,  s1});
    y[2][1] = cmulp(y[2][1], (v2f){  C,  -C}, (v2f){  C,   C});
    y[2][2] = (v2f){y[2][2].y, -y[2][2].x};
    y[2][3] = cmulp(y[2][3], (v2f){ -C,  -C}, (v2f){  C,  -C});
    y[3][1] = cmulp(y[3][1], (v2f){ s1, -c1}, (v2f){ c1,  s1});
    y[3][2] = cmulp(y[3][2], (v2f){ -C,  -C}, (v2f){  C,  -C});
    y[3][3] = cmulp(y[3][3], (v2f){-c1,  s1}, (v2f){-s1, -c1});
    #pragma unroll
    for (int k1 = 0; k1 < 4; ++k1)
        dft4(y[0][k1], y[1][k1], y[2][k1], y[3][k1],
             X[k1], X[k1 + 4], X[k1 + 8], X[k1 + 12]);
}

static __device__ __forceinline__ float kbw(const float* kt, float zz) {
    float t = fmaxf(zz * (float)KBN, 0.0f);
    int i = (int)t;
    float fr = t - (float)i;
    float w = fmaf(fr, kt[i + 1] - kt[i], kt[i]);
    return (zz > 0.f) ? w : 0.f;
}

// bucket from trajectory (identical in count & scatter)
static __device__ __forceinline__ int bucket_of(int b, float t0) {
    int base0 = (int)floorf(t0);
    int m0 = base0 % GH; if (m0 < 0) m0 += GH;
    int half = (m0 >= 640) ? 1 : 0;
    int sub = (m0 - half * 640) >> 6;          // 0..9
    return (b * 2 + half) * 10 + sub;          // 0..79
}

// ---------------------------------------------------------------------------
// Kernel 0: setup
// ---------------------------------------------------------------------------
__global__ __launch_bounds__(256) void setup_kernel(
        float2* __restrict__ tw, float* __restrict__ kbt,
        float* __restrict__ axt, float* __restrict__ ayt)
{
    int idx = blockIdx.x * 256 + threadIdx.x;
    const double TWO_PI = 6.283185307179586476925286766559;
    const float BETA = beta_f();
    const float B2 = (float)(M_PI * M_PI * 19.45);
    const float SCALE = (float)(1.0 / 1099.236098591787);

    if (idx < 1280) {
        double a = -TWO_PI * ((double)idx / 1280.0);
        tw[TW1280_OFF + idx] = make_float2((float)cos(a), (float)sin(a));
    }
    if (idx < 944) {
        double a = -TWO_PI * ((double)idx / 944.0);
        tw[TW944_OFF + idx] = make_float2((float)cos(a), (float)sin(a));
    }
    if (idx < 4097) {
        float z = fminf((float)idx * (1.0f / (float)KBN), 1.0f);
        kbt[idx] = i0f_dev(BETA * sqrtf(z));
    }
    if (idx < IH) {
        float xi = (float)(idx - IH / 2) * (1.0f / (float)GH);
        float px = (float)(M_PI * (double)JW) * xi;
        float sxr = sqrtf(B2 - px * px);
        float ax = (float)JW * sinhf(sxr) / sxr;
        axt[idx] = SCALE / ax;
    }
    if (idx < IW) {
        float yj = (float)(idx - IW / 2) * (1.0f / (float)GW);
        float py = (float)(M_PI * (double)JW) * yj;
        float syr = sqrtf(B2 - py * py);
        float ay = (float)JW * sinhf(syr) / syr;
        ayt[idx] = 1.0f / ay;
    }
}

// ---------------------------------------------------------------------------
// Sort 1: 160 blocks x 2500 points, per-block LDS histogram -> blkcnt[bu][blk]
// ---------------------------------------------------------------------------
__global__ __launch_bounds__(256) void count_kernel(
        const float* __restrict__ ktraj, int* __restrict__ blkcnt)
{
    __shared__ int lh[NB];
    int tid = threadIdx.x;
    int p0  = blockIdx.x * PPB;
    if (tid < NB) lh[tid] = 0;
    __syncthreads();
    const float sx = (float)((double)GH / (2.0 * M_PI));
    for (int r = 0; r < (PPB + 255) / 256; ++r) {
        int idx = p0 + r * 256 + tid;
        if (idx < p0 + PPB && idx < NPTS) {
            int b = idx / NK;
            int k = idx % NK;
            float t0 = ktraj[(size_t)(b * 2 + 0) * NK + k] * sx;
            atomicAdd(&lh[bucket_of(b, t0)], 1);
        }
    }
    __syncthreads();
    if (tid < NB) blkcnt[tid * CBLK + blockIdx.x] = lh[tid];
}

// ---------------------------------------------------------------------------
// Sort 2: column scans (one 1024-thread block; wave w scans buckets 5w..5w+4;
// 160 cols per bucket = 3 chunks of 64)
// ---------------------------------------------------------------------------
__global__ __launch_bounds__(1024) void scan_kernel(
        const int* __restrict__ blkcnt, int* __restrict__ offm,
        int* __restrict__ bst_g)
{
    __shared__ int tots[NB];
    __shared__ int bst[NB + 1];
    int wave = threadIdx.x >> 6;
    int lane = threadIdx.x & 63;

    for (int q = 0; q < 5; ++q) {
        int bu = wave * 5 + q;
        int running = 0;
        for (int c = 0; c < (CBLK + 63) / 64; ++c) {
            int i = c * 64 + lane;
            int v = (i < CBLK) ? blkcnt[bu * CBLK + i] : 0;
            int incl = v;
            #pragma unroll
            for (int off = 1; off < 64; off <<= 1) {
                int n = __shfl_up(incl, off);
                if (lane >= off) incl += n;
            }
            if (i < CBLK) offm[bu * CBLK + i] = running + (incl - v);
            running += __shfl(incl, 63);
        }
        if (lane == 0) tots[bu] = running;
    }
    __syncthreads();
    if (threadIdx.x == 0) {
        int s = 0;
        for (int bu = 0; bu < NB; ++bu) { bst[bu] = s; s += tots[bu]; }
        bst[NB] = s;
    }
    __syncthreads();
    if (threadIdx.x < NB + 1) bst_g[threadIdx.x] = bst[threadIdx.x];
}

// ---------------------------------------------------------------------------
// Sort 3: scatter sorted records (t0, t1, idx) — LDS atomics only
// ---------------------------------------------------------------------------
__global__ __launch_bounds__(256) void scatter_kernel(
        const float* __restrict__ ktraj, const int* __restrict__ offm,
        const int* __restrict__ bst_g, float4* __restrict__ srec)
{
    __shared__ int lbase[NB];
    int tid = threadIdx.x;
    int p0  = blockIdx.x * PPB;
    if (tid < NB)
        lbase[tid] = bst_g[tid] + offm[tid * CBLK + blockIdx.x];
    __syncthreads();

    const float sx = (float)((double)GH / (2.0 * M_PI));
    const float sy = (float)((double)GW / (2.0 * M_PI));
    for (int r = 0; r < (PPB + 255) / 256; ++r) {
        int idx = p0 + r * 256 + tid;
        if (idx < p0 + PPB && idx < NPTS) {
            int b = idx / NK;
            int k = idx % NK;
            float t0 = ktraj[(size_t)(b * 2 + 0) * NK + k] * sx;
            float t1 = ktraj[(size_t)(b * 2 + 1) * NK + k] * sy;
            int bu = bucket_of(b, t0);
            int pos = atomicAdd(&lbase[bu], 1);   // LDS atomic
            float4 rr;
            rr.x = t0; rr.y = t1; rr.z = __int_as_float(idx); rr.w = 0.f;
            srec[pos] = rr;
        }
    }
}

// ---------------------------------------------------------------------------
// Kernel 1: FUSED apodize+pad+ifftshift+scale + 944-pt row FFT. 4 rows/block.
// ---------------------------------------------------------------------------
__global__ __launch_bounds__(256) void fft_row_kernel(
        const float* __restrict__ ir, const float* __restrict__ ii,
        unsigned int* __restrict__ gridh, const v2f* __restrict__ twg,
        const float* __restrict__ axt, const float* __restrict__ ayt,
        int b0, int nb)
{
    __shared__ v2f buf[4 * 948];

    int blk  = blockIdx.x;
    int lb   = blk / 160;
    int rblk = (blk % 160) * 4;
    int b    = b0 + lb;
    int tid  = threadIdx.x;
    const v2f* tw = twg + TW944_OFF;

    for (int item = tid; item < 4 * 944; item += 256) {
        int v  = item % 944;
        int rr = item / 944;
        int ri = rblk + rr;
        int i  = (ri < 320) ? ri + 320 : ri - 320;
        v2f val = (v2f){0.f, 0.f};
        int j = -1;
        if (v < (GW - IW) / 2) j = v + IW / 2;
        else if (v >= (GW + IW) / 2) j = v - (GW + IW) / 2;
        if (j >= 0) {
            float invA = axt[i] * ayt[j];
            size_t src = ((size_t)(b * IH + i)) * IW + j;
            val.x = ir[src] * invA;
            val.y = ii[src] * invA;
        }
        buf[rr * 948 + v] = val;
    }
    __syncthreads();

    if (tid < 236) {
        int r  = tid / 59;
        int k1 = tid % 59;
        int ri = rblk + r;
        int u  = (ri < 320) ? ri : ri + 640;
        unsigned int* rowp = gridh + ((size_t)(lb * GH + u)) * GWP;
        const v2f* bufr = buf + r * 948;

        v2f acc[16];
        #pragma unroll
        for (int n2 = 0; n2 < 16; ++n2) acc[n2] = (v2f){0.f, 0.f};

        v2f r59 = tw[16 * k1];
        v2f r59p = perp(r59);
        v2f w = (v2f){1.f, 0.f};
        v2f wp = (v2f){0.f, 1.f};
        for (int n1 = 0; n1 < 15; ++n1) {
            const v4f* pb = (const v4f*)(bufr + (n1 << 4));
            #pragma unroll
            for (int t4 = 0; t4 < 8; ++t4) {
                v4f q = pb[t4];
                v2f c0 = __builtin_shufflevector(q, q, 0, 1);
                v2f c1 = __builtin_shufflevector(q, q, 2, 3);
                cmacp(acc[2 * t4],     c0, w, wp);
                cmacp(acc[2 * t4 + 1], c1, w, wp);
            }
            w = cmulp(w, r59, r59p);
            wp = perp(w);
        }
        w = tw[16 * ((44 * k1) % 59)];
        wp = perp(w);
        for (int n1 = 44; n1 < 59; ++n1) {
            const v4f* pb = (const v4f*)(bufr + (n1 << 4));
            #pragma unroll
            for (int t4 = 0; t4 < 8; ++t4) {
                v4f q = pb[t4];
                v2f c0 = __builtin_shufflevector(q, q, 0, 1);
                v2f c1 = __builtin_shufflevector(q, q, 2, 3);
                cmacp(acc[2 * t4],     c0, w, wp);
                cmacp(acc[2 * t4 + 1], c1, w, wp);
            }
            w = cmulp(w, r59, r59p);
            wp = perp(w);
        }

        v2f tstep = tw[k1];
        v2f tstepp = perp(tstep);
        v2f t = (v2f){1.f, 0.f};
        v2f tp = (v2f){0.f, 1.f};
        #pragma unroll
        for (int n2 = 0; n2 < 16; ++n2) {
            acc[n2] = cmulp(acc[n2], t, tp);
            t = cmulp(t, tstep, tstepp);
            tp = perp(t);
        }

        v2f X[16];
        dft16(acc, X);
        #pragma unroll
        for (int q = 0; q < 16; ++q)
            rowp[k1 + 59 * q] = packbf(X[q]);
    }
}

// ---------------------------------------------------------------------------
// Kernel 2: 1280-pt column FFT (20*8*8), 4 cols/block, IN-PLACE packed bf16.
// ---------------------------------------------------------------------------
__global__ __launch_bounds__(256) void fft_col_kernel(
        unsigned int* __restrict__ gridh, const v2f* __restrict__ twg)
{
    __shared__ v2f buf[1280 * NC];

    int blk = blockIdx.x;
    int lb = blk / (GW / NC);
    int vb = blk % (GW / NC);
    unsigned int* baseh = gridh + (size_t)lb * GH * GWP + vb * NC;
    int tid = threadIdx.x;
    const v2f* tw = twg + TW1280_OFF;

    #pragma unroll
    for (int it = 0; it < 10; ++it) {
        int item = it * 256 + tid;
        int c  = item & (NC - 1);
        int up = item >> 2;
        int u  = (up < 320) ? up : up + 640;
        buf[up * NC + c] = unpackbf(baseh[(size_t)u * GWP + c]);
    }
    __syncthreads();

    // stage A
    {
        int c = tid & 3;
        int m = tid >> 2;
        v2f x[10];
        #pragma unroll
        for (int n = 0; n < 10; ++n)
            x[n] = buf[(n * 64 + m) * NC + c];
        __syncthreads();

        v2f A[5][4];
        #pragma unroll
        for (int bq = 0; bq < 5; ++bq) {
            v2f x0 = x[bq], x3 = x[5 + bq];
            v2f ix3 = (v2f){-x3.y, x3.x};
            A[bq][0] = x0 + x3;
            A[bq][1] = x0 + ix3;
            A[bq][2] = x0 - x3;
            A[bq][3] = x0 - ix3;
        }
        const v2f T1  = (v2f){ 0.95105651629515353f, -0.30901699437494742f};
        const v2f T2  = (v2f){ 0.80901699437494742f, -0.58778525229247312f};
        const v2f T3  = (v2f){ 0.58778525229247312f, -0.80901699437494742f};
        const v2f T4  = (v2f){ 0.30901699437494742f, -0.95105651629515353f};
        const v2f T6  = (v2f){-0.30901699437494742f, -0.95105651629515353f};
        const v2f T8  = (v2f){-0.80901699437494742f, -0.58778525229247312f};
        const v2f T9  = (v2f){-0.95105651629515353f, -0.30901699437494742f};
        const v2f T12 = (v2f){-0.80901699437494742f,  0.58778525229247312f};
        A[1][1] = cmul(A[1][1], T1);  A[2][1] = cmul(A[2][1], T2);
        A[3][1] = cmul(A[3][1], T3);  A[4][1] = cmul(A[4][1], T4);
        A[1][2] = cmul(A[1][2], T2);  A[2][2] = cmul(A[2][2], T4);
        A[3][2] = cmul(A[3][2], T6);  A[4][2] = cmul(A[4][2], T8);
        A[1][3] = cmul(A[1][3], T3);  A[2][3] = cmul(A[2][3], T6);
        A[3][3] = cmul(A[3][3], T9);  A[4][3] = cmul(A[4][3], T12);

        v2f wstep = tw[4 * m];
        v2f wstepp = perp(wstep);
        #pragma unroll
        for (int ka = 0; ka < 4; ++ka) {
            v2f Y[5];
            dft5(A[0][ka], A[1][ka], A[2][ka], A[3][ka], A[4][ka], Y);
            v2f w = (ka == 0) ? (v2f){1.f, 0.f} : tw[m * ka];
            #pragma unroll
            for (int kb = 0; kb < 5; ++kb) {
                int k1 = ka + 4 * kb;
                v2f outv = cmulp(Y[kb], w, perp(w));
                buf[(m * 20 + (k1 ^ (m & 3))) * NC + c] = outv;
                w = cmulp(w, wstep, wstepp);
            }
        }
    }
    __syncthreads();

    // stage B
    v2f T[3][8];
    #pragma unroll
    for (int ch = 0; ch < 3; ++ch) {
        int item = ch * 256 + tid;
        if (item < 640) {
            int c  = item & 3;
            int tt = item >> 2;
            int k1 = tt % 20;
            int m2 = tt / 20;

            v2f bb[8];
            #pragma unroll
            for (int m1 = 0; m1 < 8; ++m1) {
                int m = (m1 << 3) + m2;
                bb[m1] = buf[(m * 20 + (k1 ^ (m2 & 3))) * NC + c];
            }
            dft8(bb, T[ch]);

            v2f wb = tw[20 * m2];
            v2f wbp = perp(wb);
            v2f v = (v2f){1.f, 0.f};
            #pragma unroll
            for (int k21 = 0; k21 < 8; ++k21) {
                T[ch][k21] = cmulp(T[ch][k21], v, perp(v));
                v = cmulp(v, wb, wbp);
            }
        }
    }
    __syncthreads();

    #pragma unroll
    for (int ch = 0; ch < 3; ++ch) {
        int item = ch * 256 + tid;
        if (item < 640) {
            int c  = item & 3;
            int tt = item >> 2;
            int k1 = tt % 20;
            int m2 = tt / 20;
            #pragma unroll
            for (int k21 = 0; k21 < 8; ++k21)
                buf[(((k21 << 3) + m2) * 20 + k1) * NC + c] = T[ch][k21];
        }
    }
    __syncthreads();

    // stage C
    #pragma unroll
    for (int ch = 0; ch < 3; ++ch) {
        int item = ch * 256 + tid;
        if (item < 640) {
            int c   = item & 3;
            int tt  = item >> 2;
            int k1  = tt % 20;
            int k21 = tt / 20;
            v2f bb[8];
            #pragma unroll
            for (int m2 = 0; m2 < 8; ++m2)
                bb[m2] = buf[(((k21 << 3) + m2) * 20 + k1) * NC + c];
            v2f X[8];
            dft8(bb, X);
            #pragma unroll
            for (int k22 = 0; k22 < 8; ++k22) {
                int rrow = k1 + 20 * k21 + 160 * k22;
                unsigned int pk = packbf(X[k22]);
                baseh[(size_t)rrow * GWP + c] = pk;
                if (vb < 2) baseh[(size_t)rrow * GWP + GW + c] = pk;
            }
        }
    }
}

// ---------------------------------------------------------------------------
// interp core (one point)
// ---------------------------------------------------------------------------
static __device__ __forceinline__ v2f interp_point(
        const float* kt, const unsigned int* gridh, int lb, float t0, float t1)
{
    int base0 = (int)floorf(t0);
    int base1 = (int)floorf(t1);

    int   ix[JW];
    float wx[JW];
    #pragma unroll
    for (int j = 0; j < JW; ++j) {
        int kx = base0 + j - (JW / 2 - 1);
        float u = t0 - (float)kx;
        float q = u * (1.0f / 3.0f);
        wx[j] = kbw(kt, 1.0f - q * q);
        int m = kx % GH; if (m < 0) m += GH;
        ix[j] = m;
    }
    int j0u = base1 - 2;
    int a0u = j0u & ~3;
    int aw = a0u; if (aw < 0) aw += GW;
    bool need3 = ((j0u & 3) == 3);
    float wy12[12];
    #pragma unroll
    for (int t = 0; t < 12; ++t) {
        float u = t1 - (float)(a0u + t);
        float q = u * (1.0f / 3.0f);
        wy12[t] = kbw(kt, 1.0f - q * q);
    }

    v2f acc = (v2f){0.f, 0.f};
    #pragma unroll
    for (int a = 0; a < JW; ++a) {
        const uint4* p4 = (const uint4*)(gridh +
            ((size_t)(lb * GH + ix[a])) * GWP + aw);
        uint4 q0 = p4[0];
        uint4 q1 = p4[1];
        uint4 q2 = need3 ? p4[2] : make_uint4(0u, 0u, 0u, 0u);
        unsigned int qs[12] = {q0.x, q0.y, q0.z, q0.w, q1.x, q1.y, q1.z, q1.w,
                               q2.x, q2.y, q2.z, q2.w};
        v2f rr = (v2f){0.f, 0.f};
        #pragma unroll
        for (int t = 0; t < 12; ++t)
            rr += wy12[t] * unpackbf(qs[t]);
        acc += wx[a] * rr;
    }
    return acc;
}

// ---------------------------------------------------------------------------
// Kernel 3a: interp in sorted order. Region x = blockIdx&7 = (batch, rowhalf);
// each region's gather set is a 2.44 MB half-slab (fits one XCD L2).
// ---------------------------------------------------------------------------
__global__ __launch_bounds__(256) void interp_sorted_kernel(
        const unsigned int* __restrict__ gridh, const float* __restrict__ kbt,
        const float4* __restrict__ srec, const int* __restrict__ bst_g,
        float* __restrict__ out, int write_complex)
{
    int x = blockIdx.x & 7;
    int sbeg = bst_g[x * 10];
    int send = bst_g[(x + 1) * 10];
    int slot0 = blockIdx.x >> 3;
    if (sbeg + slot0 * 256 >= send) return;      // block-uniform early exit

    __shared__ float kt[4097];
    for (int t = threadIdx.x; t < 4097; t += 256) kt[t] = kbt[t];
    __syncthreads();

    for (int slot = slot0; sbeg + slot * 256 < send; slot += RSTRIDE) {
        int sidx = sbeg + slot * 256 + threadIdx.x;
        if (sidx < send) {
            float4 r = srec[sidx];
            float t0 = r.x, t1 = r.y;
            int idx = __float_as_int(r.z);
            int b = idx / NK;
            v2f acc = interp_point(kt, gridh, b, t0, t1);
            if (write_complex) {
                ((float2*)out)[idx] = make_float2(acc.x, acc.y);
            } else {
                out[idx] = acc.x;
            }
        }
    }
}

// ---------------------------------------------------------------------------
// Kernel 3b: unsorted fallback
// ---------------------------------------------------------------------------
__global__ __launch_bounds__(256) void interp_kernel(
        const float* __restrict__ ktraj, const unsigned int* __restrict__ gridh,
        const float* __restrict__ kbt,
        float* __restrict__ out, int b0, int nb, int write_complex)
{
    __shared__ float kt[4097];
    for (int t = threadIdx.x; t < 4097; t += 256) kt[t] = kbt[t];
    __syncthreads();

    int idx = blockIdx.x * 256 + threadIdx.x;
    if (idx >= nb * NK) return;
    int lb = idx / NK;
    int k  = idx % NK;
    int b  = b0 + lb;

    const float sx = (float)((double)GH / (2.0 * M_PI));
    const float sy = (float)((double)GW / (2.0 * M_PI));
    float t0 = ktraj[(size_t)(b * 2 + 0) * NK + k] * sx;
    float t1 = ktraj[(size_t)(b * 2 + 1) * NK + k] * sy;

    v2f acc = interp_point(kt, gridh, lb, t0, t1);

    size_t p = (size_t)b * NK + k;
    if (write_complex) {
        ((float2*)out)[p] = make_float2(acc.x, acc.y);
    } else {
        out[p] = acc.x;
    }
}

// ---------------------------------------------------------------------------
extern "C" void kernel_launch(void* const* d_in, const int* in_sizes, int n_in,
                              void* d_out, int out_size, void* d_ws, size_t ws_size,
                              hipStream_t stream)
{
    const float* ir = (const float*)d_in[0];   // [B,640,472,1] float32
    const float* ii = (const float*)d_in[1];   // [B,640,472,1] float32
    const float* kt = (const float*)d_in[2];   // [B,2,K] float32
    float2* tw   = (float2*)d_ws;
    float*  kbt  = (float*)((char*)d_ws + KB_OFF_B);
    float*  axt  = (float*)((char*)d_ws + AX_OFF_B);
    float*  ayt  = (float*)((char*)d_ws + AY_OFF_B);
    float*  out  = (float*)d_out;

    int write_complex = (out_size >= 2 * BATCH * NK) ? 1 : 0;

    const size_t pb16 = (size_t)GH * GWP * sizeof(unsigned int); // 4.87 MB
    size_t avail = (ws_size > TW_RESERVE_BYTES) ? ws_size - TW_RESERVE_BYTES : 0;
    int nb = 1;
    if (avail >= 4 * pb16)      nb = 4;
    else if (avail >= 2 * pb16) nb = 2;

    unsigned int* gridh = (unsigned int*)((char*)d_ws + TW_RESERVE_BYTES);
    int use_sort = (nb == 4 && ws_size >= (size_t)SORT_END_B) ? 1 : 0;
    int*    blkcnt = (int*)((char*)d_ws + BLKCNT_OFF_B);
    int*    offm   = (int*)((char*)d_ws + OFFM_OFF_B);
    int*    bstg   = (int*)((char*)d_ws + BST_OFF_B);
    float4* srec   = (float4*)((char*)d_ws + SREC_OFF_B);

    setup_kernel<<<17, 256, 0, stream>>>(tw, kbt, axt, ayt);

    if (use_sort) {
        count_kernel<<<CBLK, 256, 0, stream>>>(kt, blkcnt);
        scan_kernel<<<1, 1024, 0, stream>>>(blkcnt, offm, bstg);
        scatter_kernel<<<CBLK, 256, 0, stream>>>(kt, offm, bstg, srec);

        fft_row_kernel<<<4 * 160, 256, 0, stream>>>(ir, ii, gridh, (const v2f*)tw, axt, ayt, 0, 4);
        fft_col_kernel<<<4 * (GW / NC), 256, 0, stream>>>(gridh, (const v2f*)tw);
        interp_sorted_kernel<<<NIBLK, 256, 0, stream>>>(gridh, kbt, srec, bstg, out, write_complex);
    } else {
        for (int b0 = 0; b0 < BATCH; b0 += nb) {
            fft_row_kernel<<<nb * 160, 256, 0, stream>>>(ir, ii, gridh, (const v2f*)tw, axt, ayt, b0, nb);
            fft_col_kernel<<<nb * (GW / NC), 256, 0, stream>>>(gridh, (const v2f*)tw);
            interp_kernel<<<(nb * NK + 255) / 256, 256, 0, stream>>>(kt, gridh, kbt, out, b0, nb, write_complex);
        }
    }
}

// Round 20
// 151.390 us; speedup vs baseline: 2.1759x; 1.0510x over previous
//
#include <hip/hip_runtime.h>
#include <math.h>

// Problem constants (match reference)
#define BATCH 4
#define NK    100000
#define IH    640
#define IW    472
#define GH    1280          // oversampled grid rows = 2*IH   (1280 = 20*8*8)
#define GW    944           // oversampled grid cols = 2*IW   (944  = 59*16)
#define GWP   952           // padded row stride: 8 echo cols (window reach <= 951)
#define JW    6             // KB kernel width

// ws layout (bytes)
#define TW1280_OFF 0
#define TW944_OFF  1280
#define KB_OFF_B   18432
#define AX_OFF_B   34944
#define AY_OFF_B   37504
#define TW_RESERVE_BYTES 65536

#define KBN 4095
#define NC 4

// ---- sort constants (atomic-free counting sort, scan fused into scatter) ----
#define NPTS   (BATCH * NK)            // 400000
#define CBLK   160                     // count/scatter blocks
#define PPB    2500                    // points per block (160*2500 = 400000)
#define NB     80                      // buckets: (b*2+half)*10 + subtile
#define RSTRIDE 200
#define NIBLK  (8 * RSTRIDE)           // interp blocks (8 XCD regions)

#define BLKCNT_OFF_B (32u * 1024 * 1024)            // NB*CBLK ints = 51200 B
#define BST_OFF_B    (BLKCNT_OFF_B + 64u * 1024)    // 81 ints (by interp)
#define SREC_OFF_B   (BST_OFF_B + 4096)             // NPTS float4 = 6.4 MB
#define SORT_END_B   (SREC_OFF_B + 6406144)

typedef float v2f __attribute__((ext_vector_type(2)));
typedef float v4f __attribute__((ext_vector_type(4)));

static __device__ __forceinline__ float beta_f() {
    return (float)(M_PI * 4.410215414239989);   // pi*sqrt(19.45)
}

static __device__ __forceinline__ float i0f_dev(float x) {
    if (x < 3.75f) {
        float t = x * (1.0f / 3.75f);
        t *= t;
        return 1.0f + t*(3.5156229f + t*(3.0899424f + t*(1.2067492f +
               t*(0.2659732f + t*(0.0360768f + t*0.0045813f)))));
    } else {
        float t = 3.75f / x;
        float p = 0.39894228f + t*(0.01328592f + t*(0.00225319f + t*(-0.00157565f +
                  t*(0.00916281f + t*(-0.02057706f + t*(0.02635537f +
                  t*(-0.01647633f + t*0.00392377f)))))));
        return p * expf(x) / sqrtf(x);
    }
}

// ---- packed complex helpers
static __device__ __forceinline__ v2f perp(v2f w) { return (v2f){-w.y, w.x}; }
static __device__ __forceinline__ v2f cmulp(v2f x, v2f w, v2f wp) {
    v2f xr = __builtin_shufflevector(x, x, 0, 0);
    v2f xi = __builtin_shufflevector(x, x, 1, 1);
    return xr * w + xi * wp;
}
static __device__ __forceinline__ v2f cmul(v2f a, v2f b) { return cmulp(a, b, perp(b)); }
static __device__ __forceinline__ void cmacp(v2f& acc, v2f x, v2f w, v2f wp) {
    v2f xr = __builtin_shufflevector(x, x, 0, 0);
    v2f xi = __builtin_shufflevector(x, x, 1, 1);
    acc += xr * w;
    acc += xi * wp;
}

static __device__ __forceinline__ unsigned int f2bf(float f) {
    unsigned int u = __float_as_uint(f);
    return (u + 0x7FFFu + ((u >> 16) & 1u)) >> 16;
}
static __device__ __forceinline__ unsigned int packbf(v2f v) {
    return f2bf(v.x) | (f2bf(v.y) << 16);
}
static __device__ __forceinline__ v2f unpackbf(unsigned int p) {
    return (v2f){__uint_as_float(p << 16), __uint_as_float(p & 0xFFFF0000u)};
}

static __device__ __forceinline__ void dft4(v2f a0, v2f a1, v2f a2, v2f a3,
                                            v2f& o0, v2f& o1, v2f& o2, v2f& o3)
{
    v2f t0 = a0 + a2, t1 = a0 - a2;
    v2f t2 = a1 + a3, t3 = a1 - a3;
    o0 = t0 + t2;
    o2 = t0 - t2;
    v2f nit3 = (v2f){t3.y, -t3.x};
    o1 = t1 + nit3;
    o3 = t1 - nit3;
}

static __device__ __forceinline__ void dft8(const v2f* b, v2f* X)
{
    v2f e0, e1, e2, e3, o0, o1, o2, o3;
    dft4(b[0], b[2], b[4], b[6], e0, e1, e2, e3);
    dft4(b[1], b[3], b[5], b[7], o0, o1, o2, o3);
    const float C = 0.70710678118654752f;
    v2f m1 = cmulp(o1, (v2f){ C, -C}, (v2f){C,  C});
    v2f m2 = (v2f){o2.y, -o2.x};
    v2f m3 = cmulp(o3, (v2f){-C, -C}, (v2f){C, -C});
    X[0] = e0 + o0; X[4] = e0 - o0;
    X[1] = e1 + m1; X[5] = e1 - m1;
    X[2] = e2 + m2; X[6] = e2 - m2;
    X[3] = e3 + m3; X[7] = e3 - m3;
}

static __device__ __forceinline__ void dft5(v2f a0, v2f a1, v2f a2, v2f a3, v2f a4,
                                            v2f* X)
{
    const float c1 = 0.30901699437494742f, s1 = 0.95105651629515353f;
    const float c2 = -0.80901699437494742f, s2 = 0.58778525229247312f;
    v2f t1 = a1 + a4, d1 = a1 - a4;
    v2f t2 = a2 + a3, d2 = a2 - a3;
    X[0] = a0 + t1 + t2;
    v2f e1 = a0 + c1 * t1 + c2 * t2;
    v2f o1 = s1 * d1 + s2 * d2;
    v2f e2 = a0 + c2 * t1 + c1 * t2;
    v2f o2 = s2 * d1 - s1 * d2;
    X[1] = (v2f){e1.x + o1.y, e1.y - o1.x};
    X[4] = (v2f){e1.x - o1.y, e1.y + o1.x};
    X[2] = (v2f){e2.x + o2.y, e2.y - o2.x};
    X[3] = (v2f){e2.x - o2.y, e2.y + o2.x};
}

static __device__ __forceinline__ void dft16(const v2f* a, v2f* X)
{
    v2f y[4][4];
    #pragma unroll
    for (int n2 = 0; n2 < 4; ++n2)
        dft4(a[n2], a[4 + n2], a[8 + n2], a[12 + n2],
             y[n2][0], y[n2][1], y[n2][2], y[n2][3]);
    const float C  = 0.70710678118654752f;
    const float c1 = 0.92387953251128676f, s1 = 0.38268343236508977f;
    y[1][1] = cmulp(y[1][1], (v2f){ c1, -s1}, (v2f){ s1,  c1});
    y[1][2] = cmulp(y[1][2], (v2f){  C,  -C}, (v2f){  C,   C});
    y[1][3] = cmulp(y[1][3], (v2f){ s1, -c1}, (v2f){ c1,  s1});
    y[2][1] = cmulp(y[2][1], (v2f){  C,  -C}, (v2f){  C,   C});
    y[2][2] = (v2f){y[2][2].y, -y[2][2].x};
    y[2][3] = cmulp(y[2][3], (v2f){ -C,  -C}, (v2f){  C,  -C});
    y[3][1] = cmulp(y[3][1], (v2f){ s1, -c1}, (v2f){ c1,  s1});
    y[3][2] = cmulp(y[3][2], (v2f){ -C,  -C}, (v2f){  C,  -C});
    y[3][3] = cmulp(y[3][3], (v2f){-c1,  s1}, (v2f){-s1, -c1});
    #pragma unroll
    for (int k1 = 0; k1 < 4; ++k1)
        dft4(y[0][k1], y[1][k1], y[2][k1], y[3][k1],
             X[k1], X[k1 + 4], X[k1 + 8], X[k1 + 12]);
}

static __device__ __forceinline__ float kbw(const float* kt, float zz) {
    float t = fmaxf(zz * (float)KBN, 0.0f);
    int i = (int)t;
    float fr = t - (float)i;
    float w = fmaf(fr, kt[i + 1] - kt[i], kt[i]);
    return (zz > 0.f) ? w : 0.f;
}

// bucket from trajectory (identical in count & scatter)
static __device__ __forceinline__ int bucket_of(int b, float t0) {
    int base0 = (int)floorf(t0);
    int m0 = base0 % GH; if (m0 < 0) m0 += GH;
    int half = (m0 >= 640) ? 1 : 0;
    int sub = (m0 - half * 640) >> 6;          // 0..9
    return (b * 2 + half) * 10 + sub;          // 0..79
}

// ---------------------------------------------------------------------------
// Kernel 0: FUSED setup (blocks 0..16) + count histograms (blocks 17..176)
// ---------------------------------------------------------------------------
__global__ __launch_bounds__(256) void setup_count_kernel(
        float2* __restrict__ tw, float* __restrict__ kbt,
        float* __restrict__ axt, float* __restrict__ ayt,
        const float* __restrict__ ktraj, int* __restrict__ blkcnt,
        int do_count)
{
    if ((int)blockIdx.x < 17) {
        int idx = blockIdx.x * 256 + threadIdx.x;
        const double TWO_PI = 6.283185307179586476925286766559;
        const float BETA = beta_f();
        const float B2 = (float)(M_PI * M_PI * 19.45);
        const float SCALE = (float)(1.0 / 1099.236098591787);

        if (idx < 1280) {
            double a = -TWO_PI * ((double)idx / 1280.0);
            tw[TW1280_OFF + idx] = make_float2((float)cos(a), (float)sin(a));
        }
        if (idx < 944) {
            double a = -TWO_PI * ((double)idx / 944.0);
            tw[TW944_OFF + idx] = make_float2((float)cos(a), (float)sin(a));
        }
        if (idx < 4097) {
            float z = fminf((float)idx * (1.0f / (float)KBN), 1.0f);
            kbt[idx] = i0f_dev(BETA * sqrtf(z));
        }
        if (idx < IH) {
            float xi = (float)(idx - IH / 2) * (1.0f / (float)GH);
            float px = (float)(M_PI * (double)JW) * xi;
            float sxr = sqrtf(B2 - px * px);
            float ax = (float)JW * sinhf(sxr) / sxr;
            axt[idx] = SCALE / ax;
        }
        if (idx < IW) {
            float yj = (float)(idx - IW / 2) * (1.0f / (float)GW);
            float py = (float)(M_PI * (double)JW) * yj;
            float syr = sqrtf(B2 - py * py);
            float ay = (float)JW * sinhf(syr) / syr;
            ayt[idx] = 1.0f / ay;
        }
    } else if (do_count) {
        __shared__ int lh[NB];
        int blk = blockIdx.x - 17;            // 0..159
        int tid = threadIdx.x;
        int p0  = blk * PPB;
        if (tid < NB) lh[tid] = 0;
        __syncthreads();
        const float sx = (float)((double)GH / (2.0 * M_PI));
        for (int r = 0; r < (PPB + 255) / 256; ++r) {
            int idx = p0 + r * 256 + tid;
            if (idx < p0 + PPB) {
                int b = idx / NK;
                int k = idx % NK;
                float t0 = ktraj[(size_t)(b * 2 + 0) * NK + k] * sx;
                atomicAdd(&lh[bucket_of(b, t0)], 1);
            }
        }
        __syncthreads();
        if (tid < NB) blkcnt[tid * CBLK + blk] = lh[tid];
    }
}

// ---------------------------------------------------------------------------
// Sort: scatter with LOCAL scan — each block redundantly computes from the
// 51 KB blkcnt matrix: bucket totals, 80-bucket exclusive scan (bst), and
// its own per-bucket exclusive column prefix. Then scatters sorted records.
// Block 0 additionally publishes bst to global for interp.
// ---------------------------------------------------------------------------
__global__ __launch_bounds__(256) void scatter_kernel(
        const float* __restrict__ ktraj, const int* __restrict__ blkcnt,
        int* __restrict__ bst_g, float4* __restrict__ srec)
{
    __shared__ int tot[NB];
    __shared__ int myoff[NB];
    __shared__ int bst[NB + 1];
    __shared__ int lbase[NB];
    int tid = threadIdx.x;
    int blk = blockIdx.x;                 // 0..159
    int p0  = blk * PPB;

    if (tid < NB) {
        int s = 0, mo = 0;
        const int* rowp = blkcnt + tid * CBLK;
        for (int i = 0; i < CBLK; ++i) {
            int v = rowp[i];
            if (i == blk) mo = s;
            s += v;
        }
        tot[tid] = s;
        myoff[tid] = mo;
    }
    __syncthreads();
    if (tid == 0) {
        int s = 0;
        #pragma unroll
        for (int bu = 0; bu < NB; ++bu) { bst[bu] = s; s += tot[bu]; }
        bst[NB] = s;
    }
    __syncthreads();
    if (tid < NB) lbase[tid] = bst[tid] + myoff[tid];
    if (blk == 0 && tid < NB + 1) bst_g[tid] = bst[tid];
    __syncthreads();

    const float sx = (float)((double)GH / (2.0 * M_PI));
    const float sy = (float)((double)GW / (2.0 * M_PI));
    for (int r = 0; r < (PPB + 255) / 256; ++r) {
        int idx = p0 + r * 256 + tid;
        if (idx < p0 + PPB) {
            int b = idx / NK;
            int k = idx % NK;
            float t0 = ktraj[(size_t)(b * 2 + 0) * NK + k] * sx;
            float t1 = ktraj[(size_t)(b * 2 + 1) * NK + k] * sy;
            int bu = bucket_of(b, t0);
            int pos = atomicAdd(&lbase[bu], 1);   // LDS atomic
            float4 rr;
            rr.x = t0; rr.y = t1; rr.z = __int_as_float(idx); rr.w = 0.f;
            srec[pos] = rr;
        }
    }
}

// ---------------------------------------------------------------------------
// Kernel 1: FUSED apodize+pad+ifftshift+scale + 944-pt row FFT. 4 rows/block.
// ---------------------------------------------------------------------------
__global__ __launch_bounds__(256) void fft_row_kernel(
        const float* __restrict__ ir, const float* __restrict__ ii,
        unsigned int* __restrict__ gridh, const v2f* __restrict__ twg,
        const float* __restrict__ axt, const float* __restrict__ ayt,
        int b0, int nb)
{
    __shared__ v2f buf[4 * 948];

    int blk  = blockIdx.x;
    int lb   = blk / 160;
    int rblk = (blk % 160) * 4;
    int b    = b0 + lb;
    int tid  = threadIdx.x;
    const v2f* tw = twg + TW944_OFF;

    for (int item = tid; item < 4 * 944; item += 256) {
        int v  = item % 944;
        int rr = item / 944;
        int ri = rblk + rr;
        int i  = (ri < 320) ? ri + 320 : ri - 320;
        v2f val = (v2f){0.f, 0.f};
        int j = -1;
        if (v < (GW - IW) / 2) j = v + IW / 2;
        else if (v >= (GW + IW) / 2) j = v - (GW + IW) / 2;
        if (j >= 0) {
            float invA = axt[i] * ayt[j];
            size_t src = ((size_t)(b * IH + i)) * IW + j;
            val.x = ir[src] * invA;
            val.y = ii[src] * invA;
        }
        buf[rr * 948 + v] = val;
    }
    __syncthreads();

    if (tid < 236) {
        int r  = tid / 59;
        int k1 = tid % 59;
        int ri = rblk + r;
        int u  = (ri < 320) ? ri : ri + 640;
        unsigned int* rowp = gridh + ((size_t)(lb * GH + u)) * GWP;
        const v2f* bufr = buf + r * 948;

        v2f acc[16];
        #pragma unroll
        for (int n2 = 0; n2 < 16; ++n2) acc[n2] = (v2f){0.f, 0.f};

        v2f r59 = tw[16 * k1];
        v2f r59p = perp(r59);
        v2f w = (v2f){1.f, 0.f};
        v2f wp = (v2f){0.f, 1.f};
        for (int n1 = 0; n1 < 15; ++n1) {
            const v4f* pb = (const v4f*)(bufr + (n1 << 4));
            #pragma unroll
            for (int t4 = 0; t4 < 8; ++t4) {
                v4f q = pb[t4];
                v2f c0 = __builtin_shufflevector(q, q, 0, 1);
                v2f c1 = __builtin_shufflevector(q, q, 2, 3);
                cmacp(acc[2 * t4],     c0, w, wp);
                cmacp(acc[2 * t4 + 1], c1, w, wp);
            }
            w = cmulp(w, r59, r59p);
            wp = perp(w);
        }
        w = tw[16 * ((44 * k1) % 59)];
        wp = perp(w);
        for (int n1 = 44; n1 < 59; ++n1) {
            const v4f* pb = (const v4f*)(bufr + (n1 << 4));
            #pragma unroll
            for (int t4 = 0; t4 < 8; ++t4) {
                v4f q = pb[t4];
                v2f c0 = __builtin_shufflevector(q, q, 0, 1);
                v2f c1 = __builtin_shufflevector(q, q, 2, 3);
                cmacp(acc[2 * t4],     c0, w, wp);
                cmacp(acc[2 * t4 + 1], c1, w, wp);
            }
            w = cmulp(w, r59, r59p);
            wp = perp(w);
        }

        v2f tstep = tw[k1];
        v2f tstepp = perp(tstep);
        v2f t = (v2f){1.f, 0.f};
        v2f tp = (v2f){0.f, 1.f};
        #pragma unroll
        for (int n2 = 0; n2 < 16; ++n2) {
            acc[n2] = cmulp(acc[n2], t, tp);
            t = cmulp(t, tstep, tstepp);
            tp = perp(t);
        }

        v2f X[16];
        dft16(acc, X);
        #pragma unroll
        for (int q = 0; q < 16; ++q)
            rowp[k1 + 59 * q] = packbf(X[q]);
    }
}

// ---------------------------------------------------------------------------
// Kernel 2: 1280-pt column FFT (20*8*8), 4 cols/block, IN-PLACE packed bf16.
// ---------------------------------------------------------------------------
__global__ __launch_bounds__(256) void fft_col_kernel(
        unsigned int* __restrict__ gridh, const v2f* __restrict__ twg)
{
    __shared__ v2f buf[1280 * NC];

    int blk = blockIdx.x;
    int lb = blk / (GW / NC);
    int vb = blk % (GW / NC);
    unsigned int* baseh = gridh + (size_t)lb * GH * GWP + vb * NC;
    int tid = threadIdx.x;
    const v2f* tw = twg + TW1280_OFF;

    #pragma unroll
    for (int it = 0; it < 10; ++it) {
        int item = it * 256 + tid;
        int c  = item & (NC - 1);
        int up = item >> 2;
        int u  = (up < 320) ? up : up + 640;
        buf[up * NC + c] = unpackbf(baseh[(size_t)u * GWP + c]);
    }
    __syncthreads();

    // stage A
    {
        int c = tid & 3;
        int m = tid >> 2;
        v2f x[10];
        #pragma unroll
        for (int n = 0; n < 10; ++n)
            x[n] = buf[(n * 64 + m) * NC + c];
        __syncthreads();

        v2f A[5][4];
        #pragma unroll
        for (int bq = 0; bq < 5; ++bq) {
            v2f x0 = x[bq], x3 = x[5 + bq];
            v2f ix3 = (v2f){-x3.y, x3.x};
            A[bq][0] = x0 + x3;
            A[bq][1] = x0 + ix3;
            A[bq][2] = x0 - x3;
            A[bq][3] = x0 - ix3;
        }
        const v2f T1  = (v2f){ 0.95105651629515353f, -0.30901699437494742f};
        const v2f T2  = (v2f){ 0.80901699437494742f, -0.58778525229247312f};
        const v2f T3  = (v2f){ 0.58778525229247312f, -0.80901699437494742f};
        const v2f T4  = (v2f){ 0.30901699437494742f, -0.95105651629515353f};
        const v2f T6  = (v2f){-0.30901699437494742f, -0.95105651629515353f};
        const v2f T8  = (v2f){-0.80901699437494742f, -0.58778525229247312f};
        const v2f T9  = (v2f){-0.95105651629515353f, -0.30901699437494742f};
        const v2f T12 = (v2f){-0.80901699437494742f,  0.58778525229247312f};
        A[1][1] = cmul(A[1][1], T1);  A[2][1] = cmul(A[2][1], T2);
        A[3][1] = cmul(A[3][1], T3);  A[4][1] = cmul(A[4][1], T4);
        A[1][2] = cmul(A[1][2], T2);  A[2][2] = cmul(A[2][2], T4);
        A[3][2] = cmul(A[3][2], T6);  A[4][2] = cmul(A[4][2], T8);
        A[1][3] = cmul(A[1][3], T3);  A[2][3] = cmul(A[2][3], T6);
        A[3][3] = cmul(A[3][3], T9);  A[4][3] = cmul(A[4][3], T12);

        v2f wstep = tw[4 * m];
        v2f wstepp = perp(wstep);
        #pragma unroll
        for (int ka = 0; ka < 4; ++ka) {
            v2f Y[5];
            dft5(A[0][ka], A[1][ka], A[2][ka], A[3][ka], A[4][ka], Y);
            v2f w = (ka == 0) ? (v2f){1.f, 0.f} : tw[m * ka];
            #pragma unroll
            for (int kb = 0; kb < 5; ++kb) {
                int k1 = ka + 4 * kb;
                v2f outv = cmulp(Y[kb], w, perp(w));
                buf[(m * 20 + (k1 ^ (m & 3))) * NC + c] = outv;
                w = cmulp(w, wstep, wstepp);
            }
        }
    }
    __syncthreads();

    // stage B
    v2f T[3][8];
    #pragma unroll
    for (int ch = 0; ch < 3; ++ch) {
        int item = ch * 256 + tid;
        if (item < 640) {
            int c  = item & 3;
            int tt = item >> 2;
            int k1 = tt % 20;
            int m2 = tt / 20;

            v2f bb[8];
            #pragma unroll
            for (int m1 = 0; m1 < 8; ++m1) {
                int m = (m1 << 3) + m2;
                bb[m1] = buf[(m * 20 + (k1 ^ (m2 & 3))) * NC + c];
            }
            dft8(bb, T[ch]);

            v2f wb = tw[20 * m2];
            v2f wbp = perp(wb);
            v2f v = (v2f){1.f, 0.f};
            #pragma unroll
            for (int k21 = 0; k21 < 8; ++k21) {
                T[ch][k21] = cmulp(T[ch][k21], v, perp(v));
                v = cmulp(v, wb, wbp);
            }
        }
    }
    __syncthreads();

    #pragma unroll
    for (int ch = 0; ch < 3; ++ch) {
        int item = ch * 256 + tid;
        if (item < 640) {
            int c  = item & 3;
            int tt = item >> 2;
            int k1 = tt % 20;
            int m2 = tt / 20;
            #pragma unroll
            for (int k21 = 0; k21 < 8; ++k21)
                buf[(((k21 << 3) + m2) * 20 + k1) * NC + c] = T[ch][k21];
        }
    }
    __syncthreads();

    // stage C
    #pragma unroll
    for (int ch = 0; ch < 3; ++ch) {
        int item = ch * 256 + tid;
        if (item < 640) {
            int c   = item & 3;
            int tt  = item >> 2;
            int k1  = tt % 20;
            int k21 = tt / 20;
            v2f bb[8];
            #pragma unroll
            for (int m2 = 0; m2 < 8; ++m2)
                bb[m2] = buf[(((k21 << 3) + m2) * 20 + k1) * NC + c];
            v2f X[8];
            dft8(bb, X);
            #pragma unroll
            for (int k22 = 0; k22 < 8; ++k22) {
                int rrow = k1 + 20 * k21 + 160 * k22;
                unsigned int pk = packbf(X[k22]);
                baseh[(size_t)rrow * GWP + c] = pk;
                if (vb < 2) baseh[(size_t)rrow * GWP + GW + c] = pk;
            }
        }
    }
}

// ---------------------------------------------------------------------------
// interp core (one point)
// ---------------------------------------------------------------------------
static __device__ __forceinline__ v2f interp_point(
        const float* kt, const unsigned int* gridh, int lb, float t0, float t1)
{
    int base0 = (int)floorf(t0);
    int base1 = (int)floorf(t1);

    int   ix[JW];
    float wx[JW];
    #pragma unroll
    for (int j = 0; j < JW; ++j) {
        int kx = base0 + j - (JW / 2 - 1);
        float u = t0 - (float)kx;
        float q = u * (1.0f / 3.0f);
        wx[j] = kbw(kt, 1.0f - q * q);
        int m = kx % GH; if (m < 0) m += GH;
        ix[j] = m;
    }
    int j0u = base1 - 2;
    int a0u = j0u & ~3;
    int aw = a0u; if (aw < 0) aw += GW;
    bool need3 = ((j0u & 3) == 3);
    float wy12[12];
    #pragma unroll
    for (int t = 0; t < 12; ++t) {
        float u = t1 - (float)(a0u + t);
        float q = u * (1.0f / 3.0f);
        wy12[t] = kbw(kt, 1.0f - q * q);
    }

    v2f acc = (v2f){0.f, 0.f};
    #pragma unroll
    for (int a = 0; a < JW; ++a) {
        const uint4* p4 = (const uint4*)(gridh +
            ((size_t)(lb * GH + ix[a])) * GWP + aw);
        uint4 q0 = p4[0];
        uint4 q1 = p4[1];
        uint4 q2 = need3 ? p4[2] : make_uint4(0u, 0u, 0u, 0u);
        unsigned int qs[12] = {q0.x, q0.y, q0.z, q0.w, q1.x, q1.y, q1.z, q1.w,
                               q2.x, q2.y, q2.z, q2.w};
        v2f rr = (v2f){0.f, 0.f};
        #pragma unroll
        for (int t = 0; t < 12; ++t)
            rr += wy12[t] * unpackbf(qs[t]);
        acc += wx[a] * rr;
    }
    return acc;
}

// ---------------------------------------------------------------------------
// Kernel 3a: interp in sorted order (region x = blockIdx&7 -> XCD locality)
// ---------------------------------------------------------------------------
__global__ __launch_bounds__(256) void interp_sorted_kernel(
        const unsigned int* __restrict__ gridh, const float* __restrict__ kbt,
        const float4* __restrict__ srec, const int* __restrict__ bst_g,
        float* __restrict__ out, int write_complex)
{
    int x = blockIdx.x & 7;
    int sbeg = bst_g[x * 10];
    int send = bst_g[(x + 1) * 10];
    int slot0 = blockIdx.x >> 3;
    if (sbeg + slot0 * 256 >= send) return;

    __shared__ float kt[4097];
    for (int t = threadIdx.x; t < 4097; t += 256) kt[t] = kbt[t];
    __syncthreads();

    for (int slot = slot0; sbeg + slot * 256 < send; slot += RSTRIDE) {
        int sidx = sbeg + slot * 256 + threadIdx.x;
        if (sidx < send) {
            float4 r = srec[sidx];
            float t0 = r.x, t1 = r.y;
            int idx = __float_as_int(r.z);
            int b = idx / NK;
            v2f acc = interp_point(kt, gridh, b, t0, t1);
            if (write_complex) {
                ((float2*)out)[idx] = make_float2(acc.x, acc.y);
            } else {
                out[idx] = acc.x;
            }
        }
    }
}

// ---------------------------------------------------------------------------
// Kernel 3b: unsorted fallback
// ---------------------------------------------------------------------------
__global__ __launch_bounds__(256) void interp_kernel(
        const float* __restrict__ ktraj, const unsigned int* __restrict__ gridh,
        const float* __restrict__ kbt,
        float* __restrict__ out, int b0, int nb, int write_complex)
{
    __shared__ float kt[4097];
    for (int t = threadIdx.x; t < 4097; t += 256) kt[t] = kbt[t];
    __syncthreads();

    int idx = blockIdx.x * 256 + threadIdx.x;
    if (idx >= nb * NK) return;
    int lb = idx / NK;
    int k  = idx % NK;
    int b  = b0 + lb;

    const float sx = (float)((double)GH / (2.0 * M_PI));
    const float sy = (float)((double)GW / (2.0 * M_PI));
    float t0 = ktraj[(size_t)(b * 2 + 0) * NK + k] * sx;
    float t1 = ktraj[(size_t)(b * 2 + 1) * NK + k] * sy;

    v2f acc = interp_point(kt, gridh, lb, t0, t1);

    size_t p = (size_t)b * NK + k;
    if (write_complex) {
        ((float2*)out)[p] = make_float2(acc.x, acc.y);
    } else {
        out[p] = acc.x;
    }
}

// ---------------------------------------------------------------------------
extern "C" void kernel_launch(void* const* d_in, const int* in_sizes, int n_in,
                              void* d_out, int out_size, void* d_ws, size_t ws_size,
                              hipStream_t stream)
{
    const float* ir = (const float*)d_in[0];   // [B,640,472,1] float32
    const float* ii = (const float*)d_in[1];   // [B,640,472,1] float32
    const float* kt = (const float*)d_in[2];   // [B,2,K] float32
    float2* tw   = (float2*)d_ws;
    float*  kbt  = (float*)((char*)d_ws + KB_OFF_B);
    float*  axt  = (float*)((char*)d_ws + AX_OFF_B);
    float*  ayt  = (float*)((char*)d_ws + AY_OFF_B);
    float*  out  = (float*)d_out;

    int write_complex = (out_size >= 2 * BATCH * NK) ? 1 : 0;

    const size_t pb16 = (size_t)GH * GWP * sizeof(unsigned int); // 4.87 MB
    size_t avail = (ws_size > TW_RESERVE_BYTES) ? ws_size - TW_RESERVE_BYTES : 0;
    int nb = 1;
    if (avail >= 4 * pb16)      nb = 4;
    else if (avail >= 2 * pb16) nb = 2;

    unsigned int* gridh = (unsigned int*)((char*)d_ws + TW_RESERVE_BYTES);
    int use_sort = (nb == 4 && ws_size >= (size_t)SORT_END_B) ? 1 : 0;
    int*    blkcnt = (int*)((char*)d_ws + BLKCNT_OFF_B);
    int*    bstg   = (int*)((char*)d_ws + BST_OFF_B);
    float4* srec   = (float4*)((char*)d_ws + SREC_OFF_B);

    setup_count_kernel<<<17 + CBLK, 256, 0, stream>>>(tw, kbt, axt, ayt, kt, blkcnt, use_sort);

    if (use_sort) {
        scatter_kernel<<<CBLK, 256, 0, stream>>>(kt, blkcnt, bstg, srec);
        fft_row_kernel<<<4 * 160, 256, 0, stream>>>(ir, ii, gridh, (const v2f*)tw, axt, ayt, 0, 4);
        fft_col_kernel<<<4 * (GW / NC), 256, 0, stream>>>(gridh, (const v2f*)tw);
        interp_sorted_kernel<<<NIBLK, 256, 0, stream>>>(gridh, kbt, srec, bstg, out, write_complex);
    } else {
        for (int b0 = 0; b0 < BATCH; b0 += nb) {
            fft_row_kernel<<<nb * 160, 256, 0, stream>>>(ir, ii, gridh, (const v2f*)tw, axt, ayt, b0, nb);
            fft_col_kernel<<<nb * (GW / NC), 256, 0, stream>>>(gridh, (const v2f*)tw);
            interp_kernel<<<(nb * NK + 255) / 256, 256, 0, stream>>>(kt, gridh, kbt, out, b0, nb, write_complex);
        }
    }
}